// Round 5
// baseline (209.943 us; speedup 1.0000x reference)
//
#include <hip/hip_runtime.h>
#include <hip/hip_bf16.h>
#include <math.h>

typedef unsigned short u16;
typedef unsigned int u32;
typedef __attribute__((ext_vector_type(4))) float f32x4;
typedef __attribute__((ext_vector_type(8))) short bf16x8;
typedef __attribute__((ext_vector_type(4))) unsigned short us4;
typedef __attribute__((ext_vector_type(8))) unsigned short us8;

#define DI __device__ __forceinline__

DI u16 f2b(float x){ __hip_bfloat16 h = __float2bfloat16(x); return *reinterpret_cast<u16*>(&h); }
DI float b2f(u16 u){ union { float f; u32 i; } v; v.i = ((u32)u) << 16; return v.f; }

// ------------------------------------------------------------------
// 1) weights -> bf16. WB = [Wq;Wk;Wv] (1536x512), WoB = Wo (512x512)
// ------------------------------------------------------------------
__global__ void k_cvt(const float* __restrict__ Wq, const float* __restrict__ Wk,
                      const float* __restrict__ Wv, const float* __restrict__ Wo,
                      u16* __restrict__ WB, u16* __restrict__ WoB){
  int i = blockIdx.x * 256 + threadIdx.x;
  WB[i]          = f2b(Wq[i]);
  WB[262144 + i] = f2b(Wk[i]);
  WB[524288 + i] = f2b(Wv[i]);
  WoB[i]         = f2b(Wo[i]);
}

// ------------------------------------------------------------------
// 2) pooled[b][c] = mean_n x[b][c][n]
// ------------------------------------------------------------------
__global__ __launch_bounds__(256) void k_pooled(const float* __restrict__ x, float* __restrict__ pooled){
  int row  = blockIdx.x * 4 + (threadIdx.x >> 6);
  int lane = threadIdx.x & 63;
  const float4* p = (const float4*)(x + ((size_t)row << 10));
  float4 v0 = p[lane], v1 = p[lane + 64], v2 = p[lane + 128], v3 = p[lane + 192];
  float s = (v0.x + v0.y + v0.z + v0.w) + (v1.x + v1.y + v1.z + v1.w)
          + (v2.x + v2.y + v2.z + v2.w) + (v3.x + v3.y + v3.z + v3.w);
  #pragma unroll
  for (int o = 32; o > 0; o >>= 1) s += __shfl_down(s, o, 64);
  if (lane == 0) pooled[row] = s * (1.0f / 1024.0f);
}

// ------------------------------------------------------------------
// 3) SE
// ------------------------------------------------------------------
__global__ __launch_bounds__(256) void k_se(const float* __restrict__ pooled,
    const float* __restrict__ Wse1, const float* __restrict__ bse1,
    const float* __restrict__ Wse2, const float* __restrict__ bse2,
    float* __restrict__ cw){
  __shared__ float pl[512];
  __shared__ float h1[32];
  int b = blockIdx.x, t = threadIdx.x;
  pl[t] = pooled[b * 512 + t];
  pl[t + 256] = pooled[b * 512 + t + 256];
  __syncthreads();
  if (t < 32){
    float acc = bse1[t];
    const float* w = Wse1 + t * 512;
    for (int c = 0; c < 512; c++) acc = fmaf(pl[c], w[c], acc);
    h1[t] = fmaxf(acc, 0.0f);
  }
  __syncthreads();
  for (int c = t; c < 512; c += 256){
    float acc = bse2[c];
    const float* w = Wse2 + c * 32;
    #pragma unroll
    for (int j = 0; j < 32; j++) acc = fmaf(h1[j], w[j], acc);
    cw[b * 512 + c] = 1.0f / (1.0f + expf(-acc));
  }
}

// ------------------------------------------------------------------
// 4) spatial gate (f32 — mask threshold precision-critical)
// ------------------------------------------------------------------
__global__ __launch_bounds__(256) void k_sp(const float* __restrict__ x,
    const float* __restrict__ Wsp, const float* __restrict__ bsp, float* __restrict__ mbuf){
  __shared__ float wsh[4096];
  __shared__ float part[4][512];
  int t = threadIdx.x;
  for (int i = t; i < 4096; i += 256) wsh[i] = Wsp[i];
  __syncthreads();
  int b = blockIdx.x >> 4, n0 = (blockIdx.x & 15) << 6;
  int px = t & 63, cq = t >> 6;
  const float* xp = x + ((size_t)b << 19) + ((size_t)(cq * 128) << 10) + n0 + px;
  float acc[8] = {0,0,0,0,0,0,0,0};
  for (int c = 0; c < 128; c++){
    float xv = xp[(size_t)c << 10];
    #pragma unroll
    for (int h = 0; h < 8; h++) acc[h] = fmaf(xv, wsh[(h << 9) + cq * 128 + c], acc[h]);
  }
  #pragma unroll
  for (int h = 0; h < 8; h++) part[cq][(h << 6) + px] = acc[h];
  __syncthreads();
  for (int i = t; i < 512; i += 256){
    int h = i >> 6, p = i & 63;
    float s = part[0][i] + part[1][i] + part[2][i] + part[3][i] + bsp[h];
    mbuf[(((size_t)(b * 8 + h)) << 10) + n0 + p] = 1.0f / (1.0f + expf(-s));
  }
}

// ------------------------------------------------------------------
// 5) adaptive pool 7x7, threshold, upsample -> bneg (B,8,N) in {0,-1e9}
// ------------------------------------------------------------------
__global__ void k_mask(const float* __restrict__ mbuf, float* __restrict__ bneg){
  __shared__ float sm[1024];
  __shared__ float mg[49];
  int bh = blockIdx.x, t = threadIdx.x;
  const float* mp = mbuf + ((size_t)bh << 10);
  for (int i = t; i < 1024; i += 64) sm[i] = mp[i];
  __syncthreads();
  if (t < 49){
    int ci = t / 7, cj = t % 7;
    int r0 = (ci * 32) / 7, r1 = ((ci + 1) * 32 + 6) / 7;
    int c0 = (cj * 32) / 7, c1 = ((cj + 1) * 32 + 6) / 7;
    float acc = 0.0f;
    for (int cc = c0; cc < c1; cc++){
      float rs = 0.0f;
      for (int rr = r0; rr < r1; rr++) rs += sm[rr * 32 + cc];
      acc += rs / (float)(r1 - r0);
    }
    float v = acc / (float)(c1 - c0);
    mg[t] = (v > 0.5f) ? 1.0f : 0.0f;
  }
  __syncthreads();
  for (int i = t; i < 1024; i += 64){
    int r = i >> 5, c = i & 31;
    float m = mg[((r * 7) >> 5) * 7 + ((c * 7) >> 5)];
    bneg[((size_t)bh << 10) + i] = (m > 0.5f) ? 0.0f : -1e9f;
  }
}

// ------------------------------------------------------------------
// 6) xf[b][n][c] = bf16( x[b][c][n] * cw[b][c] )
// ------------------------------------------------------------------
__global__ __launch_bounds__(256) void k_xf(const float* __restrict__ x,
    const float* __restrict__ cw, u16* __restrict__ xfB){
  __shared__ float tile[64][65];
  int bid = blockIdx.x;
  int b = bid >> 7, c0 = ((bid >> 4) & 7) << 6, n0 = (bid & 15) << 6;
  int t = threadIdx.x;
  {
    int cl = t >> 2, nc = (t & 3) << 4;
    const float* xp = x + ((size_t)(b * 512 + c0 + cl) << 10) + n0 + nc;
    float cwv = cw[b * 512 + c0 + cl];
    #pragma unroll
    for (int i = 0; i < 16; i += 4){
      float4 v = *(const float4*)(xp + i);
      tile[cl][nc + i + 0] = v.x * cwv;
      tile[cl][nc + i + 1] = v.y * cwv;
      tile[cl][nc + i + 2] = v.z * cwv;
      tile[cl][nc + i + 3] = v.w * cwv;
    }
  }
  __syncthreads();
  {
    int nl = t >> 2, cc = (t & 3) << 4;
    u16* op = xfB + ((size_t)(b * 1024 + n0 + nl) << 9) + c0 + cc;
    us8 o0, o1;
    #pragma unroll
    for (int i = 0; i < 8; i++)  o0[i] = f2b(tile[cc + i][nl]);
    #pragma unroll
    for (int i = 0; i < 8; i++)  o1[i] = f2b(tile[cc + 8 + i][nl]);
    *(us8*)op = o0;
    *(us8*)(op + 8) = o1;
  }
}

// ------------------------------------------------------------------
// 7/9) bf16 MFMA GEMM, BK=64, reg prefetch.
//   Q/K and MODE1 frags use SWAPPED mfma (tokens on lane&15, channels on
//   reg idx) -> packed us4/float4 epilogue stores. V frags unswapped ->
//   transposed+slot-permuted Vt store (packed along tokens).
// ------------------------------------------------------------------
template<int MODE>
__global__ __launch_bounds__(256) void k_gemm(const u16* __restrict__ A, const u16* __restrict__ Bw,
    const float* __restrict__ b0, const float* __restrict__ b1, const float* __restrict__ b2,
    u16* __restrict__ outQ, u16* __restrict__ outK, u16* __restrict__ outV, float* __restrict__ outF){
  __shared__ __align__(16) u16 As[128 * 72];
  __shared__ __align__(16) u16 Bs[128 * 72];
  int m0 = blockIdx.x * 128, n0 = blockIdx.y * 128;
  bool vblk = (MODE == 0) && (n0 >= 1024);
  int t = threadIdx.x, lane = t & 63, w = t >> 6;
  int wr = w >> 1, wc = w & 1;
  int g = lane >> 4, li = lane & 15;
  f32x4 acc[4][4];
  #pragma unroll
  for (int mt = 0; mt < 4; mt++)
    #pragma unroll
    for (int nt = 0; nt < 4; nt++) acc[mt][nt] = (f32x4){0.f, 0.f, 0.f, 0.f};

  int srow = t >> 1, scol = (t & 1) << 5;   // 32 u16 per thread per matrix
  const u16* ap = A  + (size_t)(m0 + srow) * 512 + scol;
  const u16* bp = Bw + (size_t)(n0 + srow) * 512 + scol;

  uint4 pa[4], pb[4];
  #pragma unroll
  for (int j = 0; j < 4; j++){ pa[j] = *(const uint4*)(ap + j * 8); pb[j] = *(const uint4*)(bp + j * 8); }

  for (int k0 = 0; k0 < 512; k0 += 64){
    #pragma unroll
    for (int j = 0; j < 4; j++){
      *(uint4*)&As[srow * 72 + scol + j * 8] = pa[j];
      *(uint4*)&Bs[srow * 72 + scol + j * 8] = pb[j];
    }
    __syncthreads();
    if (k0 < 448){
      #pragma unroll
      for (int j = 0; j < 4; j++){
        pa[j] = *(const uint4*)(ap + k0 + 64 + j * 8);
        pb[j] = *(const uint4*)(bp + k0 + 64 + j * 8);
      }
    }
    #pragma unroll
    for (int kk = 0; kk < 2; kk++){
      bf16x8 afr[4], bfr[4];
      #pragma unroll
      for (int mt = 0; mt < 4; mt++)
        afr[mt] = *(bf16x8*)&As[(wr * 64 + mt * 16 + li) * 72 + kk * 32 + g * 8];
      #pragma unroll
      for (int nt = 0; nt < 4; nt++)
        bfr[nt] = *(bf16x8*)&Bs[(wc * 64 + nt * 16 + li) * 72 + kk * 32 + g * 8];
      if (vblk){
        #pragma unroll
        for (int mt = 0; mt < 4; mt++)
          #pragma unroll
          for (int nt = 0; nt < 4; nt++)
            acc[mt][nt] = __builtin_amdgcn_mfma_f32_16x16x32_bf16(afr[mt], bfr[nt], acc[mt][nt], 0, 0, 0);
      } else {
        #pragma unroll
        for (int mt = 0; mt < 4; mt++)
          #pragma unroll
          for (int nt = 0; nt < 4; nt++)
            acc[mt][nt] = __builtin_amdgcn_mfma_f32_16x16x32_bf16(bfr[nt], afr[mt], acc[mt][nt], 0, 0, 0);
      }
    }
    __syncthreads();
  }

  #pragma unroll
  for (int mt = 0; mt < 4; mt++){
    #pragma unroll
    for (int nt = 0; nt < 4; nt++){
      if (MODE == 0 && vblk){
        // unswapped: row(4g+j)=m, col(li)=o. V -> Vt[bh][d][n'] packed us4
        int o = n0 + wc * 64 + nt * 16 + li;
        int c = o & 511, h = c >> 6, d = c & 63;
        int mb = m0 + wr * 64 + mt * 16 + (g << 2);
        int b = mb >> 10, n = mb & 1023;
        float bias = b2[c];
        int nperm = (n & ~31) + (((n >> 2) & 3) << 3) + (((n >> 4) & 1) << 2);
        us4 pk;
        #pragma unroll
        for (int j = 0; j < 4; j++) pk[j] = f2b(acc[mt][nt][j] + bias);
        *(us4*)&outV[(((size_t)(b * 8 + h)) << 16) + ((size_t)d << 10) + nperm] = pk;
      } else if (MODE == 0){
        // swapped: row(4g+j)=o, col(li)=m. Q/K -> [bh][n][d] packed us4
        int m = m0 + wr * 64 + mt * 16 + li;
        int b = m >> 10, n = m & 1023;
        int obase = n0 + wc * 64 + nt * 16;
        int which = obase >> 9;
        int c = obase & 511, h = c >> 6;
        int dloc = (c & 63) + (g << 2);
        const float* bb = which ? b1 : b0;
        float4 bias4 = *(const float4*)&bb[c + (g << 2)];
        float bk4[4] = {bias4.x, bias4.y, bias4.z, bias4.w};
        u16* base = which ? outK : outQ;
        us4 pk;
        #pragma unroll
        for (int j = 0; j < 4; j++) pk[j] = f2b(acc[mt][nt][j] + bk4[j]);
        *(us4*)&base[(((size_t)(b * 8 + h)) << 16) + ((size_t)n << 6) + dloc] = pk;
      } else {
        // MODE 1 swapped: float4 store
        int m = m0 + wr * 64 + mt * 16 + li;
        int obase = n0 + wc * 64 + nt * 16 + (g << 2);
        float4 bias4 = *(const float4*)&b0[obase];
        float4 vo = { acc[mt][nt][0] + bias4.x, acc[mt][nt][1] + bias4.y,
                      acc[mt][nt][2] + bias4.z, acc[mt][nt][3] + bias4.w };
        *(float4*)&outF[(size_t)m * 512 + obase] = vo;
      }
    }
  }
}

// ------------------------------------------------------------------
// 8) flash attention, split-KV 8-wave: waves {w,w+4} share 16 q-rows,
//    process even/odd KV tiles into LDS set 0/1, merge at end.
//    XCD-swizzled blockIdx so each bh stays on one XCD.
// ------------------------------------------------------------------
__global__ __launch_bounds__(512) void k_flash(const u16* __restrict__ Q, const u16* __restrict__ K,
    const u16* __restrict__ Vt, const float* __restrict__ bneg, u16* __restrict__ attnB){
  __shared__ __align__(16) u16 Ks[2][64 * 72];
  __shared__ __align__(16) u16 Vts[2][64 * 72];
  __shared__ float mks[2][64];
  int hw = blockIdx.x;
  int bid = ((hw & 7) << 7) + (hw >> 3);        // bijective: 1024 % 8 == 0
  int bh = bid >> 4, q0 = (bid & 15) << 6;
  int t = threadIdx.x, lane = t & 63, w = t >> 6;
  int qw = w & 3, half = w >> 2;
  int g = lane >> 4, li = lane & 15;

  const u16* Kp = K  + ((size_t)bh << 16);
  const u16* Vp = Vt + ((size_t)bh << 16);
  const float* bp = bneg + ((size_t)bh << 10);

  bf16x8 qfr0, qfr1;
  {
    const u16* qrow = Q + ((size_t)bh << 16) + ((size_t)(q0 + qw * 16 + li) << 6);
    qfr0 = *(const bf16x8*)(qrow + g * 8);
    qfr1 = *(const bf16x8*)(qrow + 32 + g * 8);
  }
  float bnq = bp[q0 + qw * 16 + li];

  f32x4 oacc[4];
  #pragma unroll
  for (int dt = 0; dt < 4; dt++) oacc[dt] = (f32x4){0.f, 0.f, 0.f, 0.f};
  float mrun = -INFINITY, lrun = 0.0f;

  // staging: 256-thread group 'sset' stages LDS set 'sset' (tiles 2i+sset)
  int tl = t & 255, sset = t >> 8;
  int sr = tl >> 2, sc = (tl & 3) << 4;
  const u16* kg = Kp + (sr << 6) + sc + (sset << 12);
  const u16* vg = Vp + (sr << 10) + sc + (sset << 6);
  uint4 kr0 = *(const uint4*)kg,       kr1 = *(const uint4*)(kg + 8);
  uint4 vr0 = *(const uint4*)vg,       vr1 = *(const uint4*)(vg + 8);
  float mr = (tl < 64) ? bp[(sset << 6) + tl] : 0.0f;

  for (int i = 0; i < 8; i++){
    __syncthreads();
    *(uint4*)&Ks[sset][sr * 72 + sc]      = kr0;
    *(uint4*)&Ks[sset][sr * 72 + sc + 8]  = kr1;
    *(uint4*)&Vts[sset][sr * 72 + sc]     = vr0;
    *(uint4*)&Vts[sset][sr * 72 + sc + 8] = vr1;
    if (tl < 64) mks[sset][tl] = mr;
    if (i < 7){
      int off = (i + 1) << 1;
      kr0 = *(const uint4*)(kg + off * 4096);
      kr1 = *(const uint4*)(kg + off * 4096 + 8);
      vr0 = *(const uint4*)(vg + off * 64);
      vr1 = *(const uint4*)(vg + off * 64 + 8);
      if (tl < 64) mr = bp[((off + sset) << 6) + tl];
    }
    __syncthreads();

    // S^T = K Q^T on set 'half'
    f32x4 sacc[4];
    #pragma unroll
    for (int mt = 0; mt < 4; mt++) sacc[mt] = (f32x4){0.f, 0.f, 0.f, 0.f};
    #pragma unroll
    for (int mt = 0; mt < 4; mt++){
      bf16x8 kfr0 = *(bf16x8*)&Ks[half][(mt * 16 + li) * 72 + g * 8];
      bf16x8 kfr1 = *(bf16x8*)&Ks[half][(mt * 16 + li) * 72 + 32 + g * 8];
      sacc[mt] = __builtin_amdgcn_mfma_f32_16x16x32_bf16(kfr0, qfr0, sacc[mt], 0, 0, 0);
      sacc[mt] = __builtin_amdgcn_mfma_f32_16x16x32_bf16(kfr1, qfr1, sacc[mt], 0, 0, 0);
    }

    float tmax = -INFINITY;
    #pragma unroll
    for (int mt = 0; mt < 4; mt++){
      float4 bk = *(const float4*)&mks[half][mt * 16 + g * 4];
      float bkk[4] = {bk.x, bk.y, bk.z, bk.w};
      #pragma unroll
      for (int j = 0; j < 4; j++){
        float s = sacc[mt][j] * 0.125f + fminf(bkk[j], bnq);
        sacc[mt][j] = s;
        tmax = fmaxf(tmax, s);
      }
    }
    tmax = fmaxf(tmax, __shfl_xor(tmax, 16, 64));
    tmax = fmaxf(tmax, __shfl_xor(tmax, 32, 64));

    // defer-max (T13): rescale only if max grew past threshold
    if (!__all(tmax <= mrun + 8.0f)){
      float mnew = fmaxf(mrun, tmax);
      float scl = __expf(mrun - mnew);
      mrun = mnew;
      lrun *= scl;
      #pragma unroll
      for (int dt = 0; dt < 4; dt++)
        #pragma unroll
        for (int j = 0; j < 4; j++) oacc[dt][j] *= scl;
    }

    float rsum = 0.0f;
    #pragma unroll
    for (int mt = 0; mt < 4; mt++)
      #pragma unroll
      for (int j = 0; j < 4; j++){
        float p = __expf(sacc[mt][j] - mrun);
        sacc[mt][j] = p;
        rsum += p;
      }
    rsum += __shfl_xor(rsum, 16, 64);
    rsum += __shfl_xor(rsum, 32, 64);
    lrun += rsum;

    bf16x8 pfr0, pfr1;
    #pragma unroll
    for (int e = 0; e < 4; e++){
      pfr0[e]     = (short)f2b(sacc[0][e]);
      pfr0[4 + e] = (short)f2b(sacc[1][e]);
      pfr1[e]     = (short)f2b(sacc[2][e]);
      pfr1[4 + e] = (short)f2b(sacc[3][e]);
    }
    #pragma unroll
    for (int dt = 0; dt < 4; dt++){
      bf16x8 vfr0 = *(bf16x8*)&Vts[half][(dt * 16 + li) * 72 + g * 8];
      bf16x8 vfr1 = *(bf16x8*)&Vts[half][(dt * 16 + li) * 72 + 32 + g * 8];
      oacc[dt] = __builtin_amdgcn_mfma_f32_16x16x32_bf16(vfr0, pfr0, oacc[dt], 0, 0, 0);
      oacc[dt] = __builtin_amdgcn_mfma_f32_16x16x32_bf16(vfr1, pfr1, oacc[dt], 0, 0, 0);
    }
  }

  // merge halves: waves 4-7 publish (m,l,O) via LDS (alias over Ks)
  __syncthreads();
  float* pm = (float*)&Ks[0][0];      // 256 f
  float* pl = pm + 256;               // 256 f
  float* po = pl + 256;               // 4096 f  (total 18432 B = sizeof Ks)
  int slot = qw * 64 + lane;
  if (half == 1){
    pm[slot] = mrun;
    pl[slot] = lrun;
    #pragma unroll
    for (int dt = 0; dt < 4; dt++) *(f32x4*)&po[slot * 16 + dt * 4] = oacc[dt];
  }
  __syncthreads();
  if (half == 0){
    float mb = pm[slot], lb = pl[slot];
    float mm = fmaxf(mrun, mb);
    float ea = __expf(mrun - mm), eb = __expf(mb - mm);
    float linv = 1.0f / (lrun * ea + lb * eb);
    int b = bh >> 3, h = bh & 7;
    u16* op = attnB + (((size_t)(b * 1024 + q0 + qw * 16 + li)) << 9) + h * 64 + g * 4;
    #pragma unroll
    for (int dt = 0; dt < 4; dt++){
      f32x4 ob = *(f32x4*)&po[slot * 16 + dt * 4];
      us4 pk;
      #pragma unroll
      for (int j = 0; j < 4; j++) pk[j] = f2b((oacc[dt][j] * ea + ob[j] * eb) * linv);
      *(us4*)(op + dt * 16) = pk;
    }
  }
}

// ------------------------------------------------------------------
// 10) LN over C + transpose to (B,C,N)
// ------------------------------------------------------------------
__global__ __launch_bounds__(256) void k_ln(const u16* __restrict__ xfB, const float* __restrict__ attnO,
    const float* __restrict__ gamma, const float* __restrict__ beta, float* __restrict__ out){
  __shared__ float mu_s[64], rs_s[64];
  __shared__ float tile[64][65];
  int b = blockIdx.x >> 4, n0 = (blockIdx.x & 15) << 6;
  int t = threadIdx.x, w = t >> 6, lane = t & 63;

  for (int r = w * 16; r < w * 16 + 16; r++){
    size_t rb = ((size_t)(b * 1024 + n0 + r)) << 9;
    const float* ap = attnO + rb + lane * 8;
    const u16*  xp = xfB + rb + lane * 8;
    float4 a0 = *(const float4*)ap;
    float4 a1 = *(const float4*)(ap + 4);
    union { uint4 v; u16 u[8]; } xv; xv.v = *(const uint4*)xp;
    float v0 = a0.x + b2f(xv.u[0]), v1 = a0.y + b2f(xv.u[1]);
    float v2 = a0.z + b2f(xv.u[2]), v3 = a0.w + b2f(xv.u[3]);
    float v4 = a1.x + b2f(xv.u[4]), v5 = a1.y + b2f(xv.u[5]);
    float v6 = a1.z + b2f(xv.u[6]), v7 = a1.w + b2f(xv.u[7]);
    float s  = v0 + v1 + v2 + v3 + v4 + v5 + v6 + v7;
    float s2 = v0*v0 + v1*v1 + v2*v2 + v3*v3 + v4*v4 + v5*v5 + v6*v6 + v7*v7;
    #pragma unroll
    for (int o = 32; o > 0; o >>= 1){ s += __shfl_xor(s, o, 64); s2 += __shfl_xor(s2, o, 64); }
    if (lane == 0){
      float mu = s * (1.0f / 512.0f);
      float var = s2 * (1.0f / 512.0f) - mu * mu;
      mu_s[r] = mu;
      rs_s[r] = 1.0f / sqrtf(var + 1e-5f);
    }
  }
  __syncthreads();

  for (int ch = 0; ch < 8; ch++){
    int c0 = ch * 64;
    {
      int r = t >> 2, cp = (t & 3) << 4;
      size_t rb = (((size_t)(b * 1024 + n0 + r)) << 9) + c0 + cp;
      float mu = mu_s[r], rstd = rs_s[r];
      #pragma unroll
      for (int i2 = 0; i2 < 2; i2++){
        float4 a0 = *(const float4*)(attnO + rb + i2 * 8);
        float4 a1 = *(const float4*)(attnO + rb + i2 * 8 + 4);
        union { uint4 v; u16 u[8]; } xv; xv.v = *(const uint4*)(xfB + rb + i2 * 8);
        float vv[8] = { a0.x + b2f(xv.u[0]), a0.y + b2f(xv.u[1]), a0.z + b2f(xv.u[2]), a0.w + b2f(xv.u[3]),
                        a1.x + b2f(xv.u[4]), a1.y + b2f(xv.u[5]), a1.z + b2f(xv.u[6]), a1.w + b2f(xv.u[7]) };
        #pragma unroll
        for (int i = 0; i < 8; i++){
          int c = c0 + cp + i2 * 8 + i;
          tile[r][cp + i2 * 8 + i] = (vv[i] - mu) * rstd * gamma[c] + beta[c];
        }
      }
    }
    __syncthreads();
    {
      int cl = t >> 2, np_ = (t & 3) << 4;
      float* op = out + (((size_t)(b * 512 + c0 + cl)) << 10) + n0 + np_;
      #pragma unroll
      for (int i = 0; i < 16; i += 4){
        float4 vo = { tile[np_ + i][cl], tile[np_ + i + 1][cl], tile[np_ + i + 2][cl], tile[np_ + i + 3][cl] };
        *(float4*)(op + i) = vo;
      }
    }
    __syncthreads();
  }
}

// ------------------------------------------------------------------
extern "C" void kernel_launch(void* const* d_in, const int* in_sizes, int n_in,
                              void* d_out, int out_size, void* d_ws, size_t ws_size,
                              hipStream_t stream){
  (void)in_sizes; (void)n_in; (void)out_size; (void)ws_size;
  const float* x    = (const float*)d_in[0];
  const float* Wq   = (const float*)d_in[1];
  const float* bq   = (const float*)d_in[2];
  const float* Wk   = (const float*)d_in[3];
  const float* bk   = (const float*)d_in[4];
  const float* Wv   = (const float*)d_in[5];
  const float* bv   = (const float*)d_in[6];
  const float* Wo   = (const float*)d_in[7];
  const float* bo   = (const float*)d_in[8];
  const float* Wsp  = (const float*)d_in[9];
  const float* bsp  = (const float*)d_in[10];
  const float* Wse1 = (const float*)d_in[11];
  const float* bse1 = (const float*)d_in[12];
  const float* Wse2 = (const float*)d_in[13];
  const float* bse2 = (const float*)d_in[14];
  const float* gamma= (const float*)d_in[15];
  const float* beta = (const float*)d_in[16];
  float* out = (float*)d_out;

  char* ws = (char*)d_ws;
  size_t off = 0;
  auto alloc = [&](size_t bytes) -> void* {
    void* p = ws + off;
    off += (bytes + 255) & ~(size_t)255;
    return p;
  };
  u16*   WB     = (u16*)  alloc(1536 * 512 * 2);
  u16*   WoB    = (u16*)  alloc(512 * 512 * 2);
  float* pooled = (float*)alloc(4096 * 4);
  float* cw     = (float*)alloc(4096 * 4);
  float* mbuf   = (float*)alloc(65536 * 4);
  float* bneg   = (float*)alloc(65536 * 4);
  u16*   xfB    = (u16*)  alloc((size_t)8192 * 512 * 2);
  u16*   Qb     = (u16*)  alloc(8388608);
  u16*   Kb     = (u16*)  alloc(8388608);
  u16*   VtG    = (u16*)  alloc(8388608);
  u16*   attnB  = (u16*)  alloc(8388608);
  float* attnO  = (float*)Qb;   // alias Q+K after flash

  k_cvt   <<<dim3(1024), dim3(256), 0, stream>>>(Wq, Wk, Wv, Wo, WB, WoB);
  k_pooled<<<dim3(1024), dim3(256), 0, stream>>>(x, pooled);
  k_se    <<<dim3(8),    dim3(256), 0, stream>>>(pooled, Wse1, bse1, Wse2, bse2, cw);
  k_sp    <<<dim3(128),  dim3(256), 0, stream>>>(x, Wsp, bsp, mbuf);
  k_mask  <<<dim3(64),   dim3(64),  0, stream>>>(mbuf, bneg);
  k_xf    <<<dim3(1024), dim3(256), 0, stream>>>(x, cw, xfB);
  k_gemm<0><<<dim3(64, 12), dim3(256), 0, stream>>>(xfB, WB, bq, bk, bv, Qb, Kb, VtG, (float*)nullptr);
  k_flash <<<dim3(1024), dim3(512), 0, stream>>>(Qb, Kb, VtG, bneg, attnB);
  k_gemm<1><<<dim3(64, 4), dim3(256), 0, stream>>>(attnB, WoB, bo, bo, bo, nullptr, nullptr, nullptr, attnO);
  k_ln    <<<dim3(128),  dim3(256), 0, stream>>>(xfB, attnO, gamma, beta, out);
}

// Round 6
// 207.729 us; speedup vs baseline: 1.0107x; 1.0107x over previous
//
#include <hip/hip_runtime.h>
#include <hip/hip_bf16.h>
#include <math.h>

typedef unsigned short u16;
typedef unsigned int u32;
typedef __attribute__((ext_vector_type(4))) float f32x4;
typedef __attribute__((ext_vector_type(8))) short bf16x8;
typedef __attribute__((ext_vector_type(4))) unsigned short us4;
typedef __attribute__((ext_vector_type(8))) unsigned short us8;

#define DI __device__ __forceinline__

DI u16 f2b(float x){ __hip_bfloat16 h = __float2bfloat16(x); return *reinterpret_cast<u16*>(&h); }
DI float b2f(u16 u){ union { float f; u32 i; } v; v.i = ((u32)u) << 16; return v.f; }

// ------------------------------------------------------------------
// 1) weights -> bf16. WB = [Wq;Wk;Wv] (1536x512), WoB = Wo (512x512)
// ------------------------------------------------------------------
__global__ void k_cvt(const float* __restrict__ Wq, const float* __restrict__ Wk,
                      const float* __restrict__ Wv, const float* __restrict__ Wo,
                      u16* __restrict__ WB, u16* __restrict__ WoB){
  int i = blockIdx.x * 256 + threadIdx.x;
  WB[i]          = f2b(Wq[i]);
  WB[262144 + i] = f2b(Wk[i]);
  WB[524288 + i] = f2b(Wv[i]);
  WoB[i]         = f2b(Wo[i]);
}

// ------------------------------------------------------------------
// 2) pooled[b][c] = mean_n x[b][c][n]
// ------------------------------------------------------------------
__global__ __launch_bounds__(256) void k_pooled(const float* __restrict__ x, float* __restrict__ pooled){
  int row  = blockIdx.x * 4 + (threadIdx.x >> 6);
  int lane = threadIdx.x & 63;
  const float4* p = (const float4*)(x + ((size_t)row << 10));
  float4 v0 = p[lane], v1 = p[lane + 64], v2 = p[lane + 128], v3 = p[lane + 192];
  float s = (v0.x + v0.y + v0.z + v0.w) + (v1.x + v1.y + v1.z + v1.w)
          + (v2.x + v2.y + v2.z + v2.w) + (v3.x + v3.y + v3.z + v3.w);
  #pragma unroll
  for (int o = 32; o > 0; o >>= 1) s += __shfl_down(s, o, 64);
  if (lane == 0) pooled[row] = s * (1.0f / 1024.0f);
}

// ------------------------------------------------------------------
// 3) SE
// ------------------------------------------------------------------
__global__ __launch_bounds__(256) void k_se(const float* __restrict__ pooled,
    const float* __restrict__ Wse1, const float* __restrict__ bse1,
    const float* __restrict__ Wse2, const float* __restrict__ bse2,
    float* __restrict__ cw){
  __shared__ float pl[512];
  __shared__ float h1[32];
  int b = blockIdx.x, t = threadIdx.x;
  pl[t] = pooled[b * 512 + t];
  pl[t + 256] = pooled[b * 512 + t + 256];
  __syncthreads();
  if (t < 32){
    float acc = bse1[t];
    const float* w = Wse1 + t * 512;
    for (int c = 0; c < 512; c++) acc = fmaf(pl[c], w[c], acc);
    h1[t] = fmaxf(acc, 0.0f);
  }
  __syncthreads();
  for (int c = t; c < 512; c += 256){
    float acc = bse2[c];
    const float* w = Wse2 + c * 32;
    #pragma unroll
    for (int j = 0; j < 32; j++) acc = fmaf(h1[j], w[j], acc);
    cw[b * 512 + c] = 1.0f / (1.0f + expf(-acc));
  }
}

// ------------------------------------------------------------------
// 4) spatial gate (f32 — mask threshold precision-critical)
// ------------------------------------------------------------------
__global__ __launch_bounds__(256) void k_sp(const float* __restrict__ x,
    const float* __restrict__ Wsp, const float* __restrict__ bsp, float* __restrict__ mbuf){
  __shared__ float wsh[4096];
  __shared__ float part[4][512];
  int t = threadIdx.x;
  for (int i = t; i < 4096; i += 256) wsh[i] = Wsp[i];
  __syncthreads();
  int b = blockIdx.x >> 4, n0 = (blockIdx.x & 15) << 6;
  int px = t & 63, cq = t >> 6;
  const float* xp = x + ((size_t)b << 19) + ((size_t)(cq * 128) << 10) + n0 + px;
  float acc[8] = {0,0,0,0,0,0,0,0};
  for (int c = 0; c < 128; c++){
    float xv = xp[(size_t)c << 10];
    #pragma unroll
    for (int h = 0; h < 8; h++) acc[h] = fmaf(xv, wsh[(h << 9) + cq * 128 + c], acc[h]);
  }
  #pragma unroll
  for (int h = 0; h < 8; h++) part[cq][(h << 6) + px] = acc[h];
  __syncthreads();
  for (int i = t; i < 512; i += 256){
    int h = i >> 6, p = i & 63;
    float s = part[0][i] + part[1][i] + part[2][i] + part[3][i] + bsp[h];
    mbuf[(((size_t)(b * 8 + h)) << 10) + n0 + p] = 1.0f / (1.0f + expf(-s));
  }
}

// ------------------------------------------------------------------
// 5) adaptive pool 7x7, threshold, upsample -> bneg (B,8,N) in {0,-1e9}
// ------------------------------------------------------------------
__global__ void k_mask(const float* __restrict__ mbuf, float* __restrict__ bneg){
  __shared__ float sm[1024];
  __shared__ float mg[49];
  int bh = blockIdx.x, t = threadIdx.x;
  const float* mp = mbuf + ((size_t)bh << 10);
  for (int i = t; i < 1024; i += 64) sm[i] = mp[i];
  __syncthreads();
  if (t < 49){
    int ci = t / 7, cj = t % 7;
    int r0 = (ci * 32) / 7, r1 = ((ci + 1) * 32 + 6) / 7;
    int c0 = (cj * 32) / 7, c1 = ((cj + 1) * 32 + 6) / 7;
    float acc = 0.0f;
    for (int cc = c0; cc < c1; cc++){
      float rs = 0.0f;
      for (int rr = r0; rr < r1; rr++) rs += sm[rr * 32 + cc];
      acc += rs / (float)(r1 - r0);
    }
    float v = acc / (float)(c1 - c0);
    mg[t] = (v > 0.5f) ? 1.0f : 0.0f;
  }
  __syncthreads();
  for (int i = t; i < 1024; i += 64){
    int r = i >> 5, c = i & 31;
    float m = mg[((r * 7) >> 5) * 7 + ((c * 7) >> 5)];
    bneg[((size_t)bh << 10) + i] = (m > 0.5f) ? 0.0f : -1e9f;
  }
}

// ------------------------------------------------------------------
// 6) xf[b][n][c] = bf16( x[b][c][n] * cw[b][c] )
// ------------------------------------------------------------------
__global__ __launch_bounds__(256) void k_xf(const float* __restrict__ x,
    const float* __restrict__ cw, u16* __restrict__ xfB){
  __shared__ float tile[64][65];
  int bid = blockIdx.x;
  int b = bid >> 7, c0 = ((bid >> 4) & 7) << 6, n0 = (bid & 15) << 6;
  int t = threadIdx.x;
  {
    int cl = t >> 2, nc = (t & 3) << 4;
    const float* xp = x + ((size_t)(b * 512 + c0 + cl) << 10) + n0 + nc;
    float cwv = cw[b * 512 + c0 + cl];
    #pragma unroll
    for (int i = 0; i < 16; i += 4){
      float4 v = *(const float4*)(xp + i);
      tile[cl][nc + i + 0] = v.x * cwv;
      tile[cl][nc + i + 1] = v.y * cwv;
      tile[cl][nc + i + 2] = v.z * cwv;
      tile[cl][nc + i + 3] = v.w * cwv;
    }
  }
  __syncthreads();
  {
    int nl = t >> 2, cc = (t & 3) << 4;
    u16* op = xfB + ((size_t)(b * 1024 + n0 + nl) << 9) + c0 + cc;
    us8 o0, o1;
    #pragma unroll
    for (int i = 0; i < 8; i++)  o0[i] = f2b(tile[cc + i][nl]);
    #pragma unroll
    for (int i = 0; i < 8; i++)  o1[i] = f2b(tile[cc + 8 + i][nl]);
    *(us8*)op = o0;
    *(us8*)(op + 8) = o1;
  }
}

// ------------------------------------------------------------------
// 7/9) bf16 MFMA GEMM, BK=64, reg prefetch, LDS-staged coalesced epilogue.
//   Q/K use SWAPPED mfma (tokens on lane&15, channels on reg idx);
//   V unswapped -> transposed + slot-permuted C_lds -> contiguous Vt rows.
//   MODE 1 (Wo): swapped, direct float4 stores (full 64B lines).
// ------------------------------------------------------------------
template<int MODE>
__global__ __launch_bounds__(256) void k_gemm(const u16* __restrict__ A, const u16* __restrict__ Bw,
    const float* __restrict__ b0, const float* __restrict__ b1, const float* __restrict__ b2,
    u16* __restrict__ outQ, u16* __restrict__ outK, u16* __restrict__ outV, float* __restrict__ outF){
  __shared__ __align__(16) u16 smem[18432];          // As/Bs (36864B) | C_lds 128x136 (34816B)
  u16* As = smem;
  u16* Bs = smem + 9216;
  int m0 = blockIdx.x * 128, n0 = blockIdx.y * 128;
  bool vblk = (MODE == 0) && (n0 >= 1024);
  int t = threadIdx.x, lane = t & 63, w = t >> 6;
  int wr = w >> 1, wc = w & 1;
  int g = lane >> 4, li = lane & 15;
  f32x4 acc[4][4];
  #pragma unroll
  for (int mt = 0; mt < 4; mt++)
    #pragma unroll
    for (int nt = 0; nt < 4; nt++) acc[mt][nt] = (f32x4){0.f, 0.f, 0.f, 0.f};

  int srow = t >> 1, scol = (t & 1) << 5;
  const u16* ap = A  + (size_t)(m0 + srow) * 512 + scol;
  const u16* bp = Bw + (size_t)(n0 + srow) * 512 + scol;

  uint4 pa[4], pb[4];
  #pragma unroll
  for (int j = 0; j < 4; j++){ pa[j] = *(const uint4*)(ap + j * 8); pb[j] = *(const uint4*)(bp + j * 8); }

  for (int k0 = 0; k0 < 512; k0 += 64){
    #pragma unroll
    for (int j = 0; j < 4; j++){
      *(uint4*)&As[srow * 72 + scol + j * 8] = pa[j];
      *(uint4*)&Bs[srow * 72 + scol + j * 8] = pb[j];
    }
    __syncthreads();
    if (k0 < 448){
      #pragma unroll
      for (int j = 0; j < 4; j++){
        pa[j] = *(const uint4*)(ap + k0 + 64 + j * 8);
        pb[j] = *(const uint4*)(bp + k0 + 64 + j * 8);
      }
    }
    #pragma unroll
    for (int kk = 0; kk < 2; kk++){
      bf16x8 afr[4], bfr[4];
      #pragma unroll
      for (int mt = 0; mt < 4; mt++)
        afr[mt] = *(bf16x8*)&As[(wr * 64 + mt * 16 + li) * 72 + kk * 32 + g * 8];
      #pragma unroll
      for (int nt = 0; nt < 4; nt++)
        bfr[nt] = *(bf16x8*)&Bs[(wc * 64 + nt * 16 + li) * 72 + kk * 32 + g * 8];
      if (vblk){
        #pragma unroll
        for (int mt = 0; mt < 4; mt++)
          #pragma unroll
          for (int nt = 0; nt < 4; nt++)
            acc[mt][nt] = __builtin_amdgcn_mfma_f32_16x16x32_bf16(afr[mt], bfr[nt], acc[mt][nt], 0, 0, 0);
      } else {
        #pragma unroll
        for (int mt = 0; mt < 4; mt++)
          #pragma unroll
          for (int nt = 0; nt < 4; nt++)
            acc[mt][nt] = __builtin_amdgcn_mfma_f32_16x16x32_bf16(bfr[nt], afr[mt], acc[mt][nt], 0, 0, 0);
      }
    }
    __syncthreads();
  }

  if (MODE == 1){
    // swapped: lane li = token m, reg (4g+j) = out channel. g-quartet covers
    // 64B contiguous -> full-line stores, no LDS bounce needed.
    #pragma unroll
    for (int mt = 0; mt < 4; mt++){
      #pragma unroll
      for (int nt = 0; nt < 4; nt++){
        int m = m0 + wr * 64 + mt * 16 + li;
        int obase = n0 + wc * 64 + nt * 16 + (g << 2);
        float4 bias4 = *(const float4*)&b0[obase];
        float4 vo = { acc[mt][nt][0] + bias4.x, acc[mt][nt][1] + bias4.y,
                      acc[mt][nt][2] + bias4.z, acc[mt][nt][3] + bias4.w };
        *(float4*)&outF[(size_t)m * 512 + obase] = vo;
      }
    }
    return;
  }

  // ---- MODE 0: stage C tile in LDS (pitch 136), then coalesced us8 stores
  u16* Cl = smem;
  if (vblk){
    // unswapped: lane li = o (channel), reg (4g+j) = token m.
    // Write transposed, slot-permuted: perm(n&31): [a g1 g0 j1 j0]->[g1 g0 a j1 j0]
    #pragma unroll
    for (int mt = 0; mt < 4; mt++){
      #pragma unroll
      for (int nt = 0; nt < 4; nt++){
        int ol = wc * 64 + nt * 16 + li;                  // C_lds row = channel
        float bias = b2[(n0 & 511) + ol];
        int mperm = wr * 64 + ((mt >> 1) << 5) + (g << 3) + ((mt & 1) << 2);
        us4 pk;
        #pragma unroll
        for (int j = 0; j < 4; j++) pk[j] = f2b(acc[mt][nt][j] + bias);
        *(us4*)&Cl[ol * 136 + mperm] = pk;
      }
    }
  } else {
    // swapped: lane li = token m, reg (4g+j) = channel.
    const float* bb = (n0 >> 9) ? b1 : b0;
    #pragma unroll
    for (int mt = 0; mt < 4; mt++){
      #pragma unroll
      for (int nt = 0; nt < 4; nt++){
        int ml = wr * 64 + mt * 16 + li;                  // C_lds row = token
        int ob = wc * 64 + nt * 16 + (g << 2);
        float4 bias4 = *(const float4*)&bb[(n0 & 511) + ob];
        float bk4[4] = {bias4.x, bias4.y, bias4.z, bias4.w};
        us4 pk;
        #pragma unroll
        for (int j = 0; j < 4; j++) pk[j] = f2b(acc[mt][nt][j] + bk4[j]);
        *(us4*)&Cl[ml * 136 + ob] = pk;
      }
    }
  }
  __syncthreads();

  if (vblk){
    // row r = channel (2 heads), cols = 128 permuted tokens -> 256B contiguous
    int b = m0 >> 10, nt0 = m0 & 1023;
    #pragma unroll
    for (int p = 0; p < 8; p++){
      int r = p * 16 + (t >> 4);
      int c = (n0 & 511) + r, h = c >> 6, dv = c & 63;
      us8 v = *(us8*)&Cl[r * 136 + ((t & 15) << 3)];
      *(us8*)&outV[(((size_t)(b * 8 + h)) << 16) + ((size_t)dv << 10) + nt0 + ((t & 15) << 3)] = v;
    }
  } else {
    // row r = token, 256B row = two 128B full-line chunks (2 heads)
    u16* base = (n0 >> 9) ? outK : outQ;
    #pragma unroll
    for (int p = 0; p < 8; p++){
      int r = p * 16 + (t >> 4);
      int m = m0 + r, b = m >> 10, n = m & 1023;
      int ol = (t & 15) << 3;
      int c = (n0 & 511) + ol, h = c >> 6, dv = c & 63;
      us8 v = *(us8*)&Cl[r * 136 + ol];
      *(us8*)&base[(((size_t)(b * 8 + h)) << 16) + ((size_t)n << 6) + dv] = v;
    }
  }
}

// ------------------------------------------------------------------
// 8) flash attention, swapped-operand form (round-1 structure, measured
//    45.7us) + bijective XCD swizzle + defer-max.
// ------------------------------------------------------------------
__global__ __launch_bounds__(256) void k_flash(const u16* __restrict__ Q, const u16* __restrict__ K,
    const u16* __restrict__ Vt, const float* __restrict__ bneg, u16* __restrict__ attnB){
  __shared__ __align__(16) u16 Ks[64 * 72];
  __shared__ __align__(16) u16 Vts[64 * 72];
  __shared__ float mks[64];
  int hw = blockIdx.x;
  int bid = ((hw & 7) << 7) + (hw >> 3);     // XCD swizzle: all 16 q-tiles of a bh on one XCD
  int bh = bid >> 4, q0 = (bid & 15) << 6;
  int t = threadIdx.x, lane = t & 63, w = t >> 6;
  int g = lane >> 4, li = lane & 15;

  const u16* Kp = K  + ((size_t)bh << 16);
  const u16* Vp = Vt + ((size_t)bh << 16);
  const float* bp = bneg + ((size_t)bh << 10);

  bf16x8 qfr0, qfr1;
  {
    const u16* qrow = Q + ((size_t)bh << 16) + ((size_t)(q0 + w * 16 + li) << 6);
    qfr0 = *(const bf16x8*)(qrow + g * 8);
    qfr1 = *(const bf16x8*)(qrow + 32 + g * 8);
  }
  float bnq = bp[q0 + w * 16 + li];

  f32x4 oacc[4];
  #pragma unroll
  for (int dt = 0; dt < 4; dt++) oacc[dt] = (f32x4){0.f, 0.f, 0.f, 0.f};
  float mrun = -INFINITY, lrun = 0.0f;

  int sr = t >> 2, sc = (t & 3) << 4;
  const u16* kg = Kp + ((size_t)sr << 6) + sc;
  const u16* vg = Vp + ((size_t)sr << 10) + sc;
  uint4 kr0, kr1, vr0, vr1;
  float mr = 0.0f;
  kr0 = *(const uint4*)(kg);
  kr1 = *(const uint4*)(kg + 8);
  vr0 = *(const uint4*)(vg);
  vr1 = *(const uint4*)(vg + 8);
  if (t < 64) mr = bp[t];

  for (int kt = 0; kt < 16; kt++){
    __syncthreads();
    *(uint4*)&Ks[sr * 72 + sc]      = kr0;
    *(uint4*)&Ks[sr * 72 + sc + 8]  = kr1;
    *(uint4*)&Vts[sr * 72 + sc]     = vr0;
    *(uint4*)&Vts[sr * 72 + sc + 8] = vr1;
    if (t < 64) mks[t] = mr;
    if (kt < 15){
      kr0 = *(const uint4*)(kg + (kt + 1) * 4096);
      kr1 = *(const uint4*)(kg + (kt + 1) * 4096 + 8);
      vr0 = *(const uint4*)(vg + (kt + 1) * 64);
      vr1 = *(const uint4*)(vg + (kt + 1) * 64 + 8);
      if (t < 64) mr = bp[(kt + 1) * 64 + t];
    }
    __syncthreads();

    // S^T = K Q^T : sacc[mt][j] = S[key=mt*16+4g+j][q=li]
    f32x4 sacc[4];
    #pragma unroll
    for (int mt = 0; mt < 4; mt++) sacc[mt] = (f32x4){0.f, 0.f, 0.f, 0.f};
    #pragma unroll
    for (int mt = 0; mt < 4; mt++){
      bf16x8 kfr0 = *(bf16x8*)&Ks[(mt * 16 + li) * 72 + g * 8];
      bf16x8 kfr1 = *(bf16x8*)&Ks[(mt * 16 + li) * 72 + 32 + g * 8];
      sacc[mt] = __builtin_amdgcn_mfma_f32_16x16x32_bf16(kfr0, qfr0, sacc[mt], 0, 0, 0);
      sacc[mt] = __builtin_amdgcn_mfma_f32_16x16x32_bf16(kfr1, qfr1, sacc[mt], 0, 0, 0);
    }

    float tmax = -INFINITY;
    #pragma unroll
    for (int mt = 0; mt < 4; mt++){
      float4 bk = *(const float4*)&mks[mt * 16 + g * 4];
      float bkk[4] = {bk.x, bk.y, bk.z, bk.w};
      #pragma unroll
      for (int j = 0; j < 4; j++){
        float s = sacc[mt][j] * 0.125f + fminf(bkk[j], bnq);
        sacc[mt][j] = s;
        tmax = fmaxf(tmax, s);
      }
    }
    tmax = fmaxf(tmax, __shfl_xor(tmax, 16, 64));
    tmax = fmaxf(tmax, __shfl_xor(tmax, 32, 64));

    // defer-max (T13): rescale only when max grows past threshold
    if (!__all(tmax <= mrun + 8.0f)){
      float mnew = fmaxf(mrun, tmax);
      float scl = __expf(mrun - mnew);
      mrun = mnew;
      lrun *= scl;
      #pragma unroll
      for (int dt = 0; dt < 4; dt++)
        #pragma unroll
        for (int j = 0; j < 4; j++) oacc[dt][j] *= scl;
    }

    float rsum = 0.0f;
    #pragma unroll
    for (int mt = 0; mt < 4; mt++)
      #pragma unroll
      for (int j = 0; j < 4; j++){
        float p = __expf(sacc[mt][j] - mrun);
        sacc[mt][j] = p;
        rsum += p;
      }
    rsum += __shfl_xor(rsum, 16, 64);
    rsum += __shfl_xor(rsum, 32, 64);
    lrun += rsum;

    bf16x8 pfr0, pfr1;
    #pragma unroll
    for (int e = 0; e < 4; e++){
      pfr0[e]     = (short)f2b(sacc[0][e]);
      pfr0[4 + e] = (short)f2b(sacc[1][e]);
      pfr1[e]     = (short)f2b(sacc[2][e]);
      pfr1[4 + e] = (short)f2b(sacc[3][e]);
    }
    #pragma unroll
    for (int dt = 0; dt < 4; dt++){
      bf16x8 vfr0 = *(bf16x8*)&Vts[(dt * 16 + li) * 72 + g * 8];
      bf16x8 vfr1 = *(bf16x8*)&Vts[(dt * 16 + li) * 72 + 32 + g * 8];
      oacc[dt] = __builtin_amdgcn_mfma_f32_16x16x32_bf16(vfr0, pfr0, oacc[dt], 0, 0, 0);
      oacc[dt] = __builtin_amdgcn_mfma_f32_16x16x32_bf16(vfr1, pfr1, oacc[dt], 0, 0, 0);
    }
  }

  float inv = 1.0f / lrun;
  int b = bh >> 3, h = bh & 7;
  u16* op = attnB + (((size_t)(b * 1024 + q0 + w * 16 + li)) << 9) + h * 64 + g * 4;
  #pragma unroll
  for (int dt = 0; dt < 4; dt++){
    us4 pk;
    #pragma unroll
    for (int j = 0; j < 4; j++) pk[j] = f2b(oacc[dt][j] * inv);
    *(us4*)(op + dt * 16) = pk;
  }
}

// ------------------------------------------------------------------
// 10) LN over C + transpose to (B,C,N)
// ------------------------------------------------------------------
__global__ __launch_bounds__(256) void k_ln(const u16* __restrict__ xfB, const float* __restrict__ attnO,
    const float* __restrict__ gamma, const float* __restrict__ beta, float* __restrict__ out){
  __shared__ float mu_s[64], rs_s[64];
  __shared__ float tile[64][65];
  int b = blockIdx.x >> 4, n0 = (blockIdx.x & 15) << 6;
  int t = threadIdx.x, w = t >> 6, lane = t & 63;

  for (int r = w * 16; r < w * 16 + 16; r++){
    size_t rb = ((size_t)(b * 1024 + n0 + r)) << 9;
    const float* ap = attnO + rb + lane * 8;
    const u16*  xp = xfB + rb + lane * 8;
    float4 a0 = *(const float4*)ap;
    float4 a1 = *(const float4*)(ap + 4);
    union { uint4 v; u16 u[8]; } xv; xv.v = *(const uint4*)xp;
    float v0 = a0.x + b2f(xv.u[0]), v1 = a0.y + b2f(xv.u[1]);
    float v2 = a0.z + b2f(xv.u[2]), v3 = a0.w + b2f(xv.u[3]);
    float v4 = a1.x + b2f(xv.u[4]), v5 = a1.y + b2f(xv.u[5]);
    float v6 = a1.z + b2f(xv.u[6]), v7 = a1.w + b2f(xv.u[7]);
    float s  = v0 + v1 + v2 + v3 + v4 + v5 + v6 + v7;
    float s2 = v0*v0 + v1*v1 + v2*v2 + v3*v3 + v4*v4 + v5*v5 + v6*v6 + v7*v7;
    #pragma unroll
    for (int o = 32; o > 0; o >>= 1){ s += __shfl_xor(s, o, 64); s2 += __shfl_xor(s2, o, 64); }
    if (lane == 0){
      float mu = s * (1.0f / 512.0f);
      float var = s2 * (1.0f / 512.0f) - mu * mu;
      mu_s[r] = mu;
      rs_s[r] = 1.0f / sqrtf(var + 1e-5f);
    }
  }
  __syncthreads();

  for (int ch = 0; ch < 8; ch++){
    int c0 = ch * 64;
    {
      int r = t >> 2, cp = (t & 3) << 4;
      size_t rb = (((size_t)(b * 1024 + n0 + r)) << 9) + c0 + cp;
      float mu = mu_s[r], rstd = rs_s[r];
      #pragma unroll
      for (int i2 = 0; i2 < 2; i2++){
        float4 a0 = *(const float4*)(attnO + rb + i2 * 8);
        float4 a1 = *(const float4*)(attnO + rb + i2 * 8 + 4);
        union { uint4 v; u16 u[8]; } xv; xv.v = *(const uint4*)(xfB + rb + i2 * 8);
        float vv[8] = { a0.x + b2f(xv.u[0]), a0.y + b2f(xv.u[1]), a0.z + b2f(xv.u[2]), a0.w + b2f(xv.u[3]),
                        a1.x + b2f(xv.u[4]), a1.y + b2f(xv.u[5]), a1.z + b2f(xv.u[6]), a1.w + b2f(xv.u[7]) };
        #pragma unroll
        for (int i = 0; i < 8; i++){
          int c = c0 + cp + i2 * 8 + i;
          tile[r][cp + i2 * 8 + i] = (vv[i] - mu) * rstd * gamma[c] + beta[c];
        }
      }
    }
    __syncthreads();
    {
      int cl = t >> 2, np_ = (t & 3) << 4;
      float* op = out + (((size_t)(b * 512 + c0 + cl)) << 10) + n0 + np_;
      #pragma unroll
      for (int i = 0; i < 16; i += 4){
        float4 vo = { tile[np_ + i][cl], tile[np_ + i + 1][cl], tile[np_ + i + 2][cl], tile[np_ + i + 3][cl] };
        *(float4*)(op + i) = vo;
      }
    }
    __syncthreads();
  }
}

// ------------------------------------------------------------------
extern "C" void kernel_launch(void* const* d_in, const int* in_sizes, int n_in,
                              void* d_out, int out_size, void* d_ws, size_t ws_size,
                              hipStream_t stream){
  (void)in_sizes; (void)n_in; (void)out_size; (void)ws_size;
  const float* x    = (const float*)d_in[0];
  const float* Wq   = (const float*)d_in[1];
  const float* bq   = (const float*)d_in[2];
  const float* Wk   = (const float*)d_in[3];
  const float* bk   = (const float*)d_in[4];
  const float* Wv   = (const float*)d_in[5];
  const float* bv   = (const float*)d_in[6];
  const float* Wo   = (const float*)d_in[7];
  const float* bo   = (const float*)d_in[8];
  const float* Wsp  = (const float*)d_in[9];
  const float* bsp  = (const float*)d_in[10];
  const float* Wse1 = (const float*)d_in[11];
  const float* bse1 = (const float*)d_in[12];
  const float* Wse2 = (const float*)d_in[13];
  const float* bse2 = (const float*)d_in[14];
  const float* gamma= (const float*)d_in[15];
  const float* beta = (const float*)d_in[16];
  float* out = (float*)d_out;

  char* ws = (char*)d_ws;
  size_t off = 0;
  auto alloc = [&](size_t bytes) -> void* {
    void* p = ws + off;
    off += (bytes + 255) & ~(size_t)255;
    return p;
  };
  u16*   WB     = (u16*)  alloc(1536 * 512 * 2);
  u16*   WoB    = (u16*)  alloc(512 * 512 * 2);
  float* pooled = (float*)alloc(4096 * 4);
  float* cw     = (float*)alloc(4096 * 4);
  float* mbuf   = (float*)alloc(65536 * 4);
  float* bneg   = (float*)alloc(65536 * 4);
  u16*   xfB    = (u16*)  alloc((size_t)8192 * 512 * 2);
  u16*   Qb     = (u16*)  alloc(8388608);
  u16*   Kb     = (u16*)  alloc(8388608);
  u16*   VtG    = (u16*)  alloc(8388608);
  u16*   attnB  = (u16*)  alloc(8388608);
  float* attnO  = (float*)Qb;   // alias Q+K after flash

  k_cvt   <<<dim3(1024), dim3(256), 0, stream>>>(Wq, Wk, Wv, Wo, WB, WoB);
  k_pooled<<<dim3(1024), dim3(256), 0, stream>>>(x, pooled);
  k_se    <<<dim3(8),    dim3(256), 0, stream>>>(pooled, Wse1, bse1, Wse2, bse2, cw);
  k_sp    <<<dim3(128),  dim3(256), 0, stream>>>(x, Wsp, bsp, mbuf);
  k_mask  <<<dim3(64),   dim3(64),  0, stream>>>(mbuf, bneg);
  k_xf    <<<dim3(1024), dim3(256), 0, stream>>>(x, cw, xfB);
  k_gemm<0><<<dim3(64, 12), dim3(256), 0, stream>>>(xfB, WB, bq, bk, bv, Qb, Kb, VtG, (float*)nullptr);
  k_flash <<<dim3(1024), dim3(256), 0, stream>>>(Qb, Kb, VtG, bneg, attnB);
  k_gemm<1><<<dim3(64, 4), dim3(256), 0, stream>>>(attnB, WoB, bo, bo, bo, nullptr, nullptr, nullptr, attnO);
  k_ln    <<<dim3(128),  dim3(256), 0, stream>>>(xfB, attnO, gamma, beta, out);
}

// Round 7
// 169.335 us; speedup vs baseline: 1.2398x; 1.2267x over previous
//
#include <hip/hip_runtime.h>
#include <hip/hip_bf16.h>
#include <math.h>

typedef unsigned short u16;
typedef unsigned int u32;
typedef __attribute__((ext_vector_type(4))) float f32x4;
typedef __attribute__((ext_vector_type(8))) short bf16x8;
typedef __attribute__((ext_vector_type(4))) unsigned short us4;
typedef __attribute__((ext_vector_type(8))) unsigned short us8;

#define DI __device__ __forceinline__

DI u16 f2b(float x){ __hip_bfloat16 h = __float2bfloat16(x); return *reinterpret_cast<u16*>(&h); }
DI float b2f(u16 u){ union { float f; u32 i; } v; v.i = ((u32)u) << 16; return v.f; }

// ------------------------------------------------------------------
// 1) weights -> bf16. WB = [Wq;Wk;Wv] (1536x512), WoB = Wo (512x512)
// ------------------------------------------------------------------
__global__ void k_cvt(const float* __restrict__ Wq, const float* __restrict__ Wk,
                      const float* __restrict__ Wv, const float* __restrict__ Wo,
                      u16* __restrict__ WB, u16* __restrict__ WoB){
  int i = blockIdx.x * 256 + threadIdx.x;
  WB[i]          = f2b(Wq[i]);
  WB[262144 + i] = f2b(Wk[i]);
  WB[524288 + i] = f2b(Wv[i]);
  WoB[i]         = f2b(Wo[i]);
}

// ------------------------------------------------------------------
// 2) pooled[b][c] = mean_n x[b][c][n]
// ------------------------------------------------------------------
__global__ __launch_bounds__(256) void k_pooled(const float* __restrict__ x, float* __restrict__ pooled){
  int row  = blockIdx.x * 4 + (threadIdx.x >> 6);
  int lane = threadIdx.x & 63;
  const float4* p = (const float4*)(x + ((size_t)row << 10));
  float4 v0 = p[lane], v1 = p[lane + 64], v2 = p[lane + 128], v3 = p[lane + 192];
  float s = (v0.x + v0.y + v0.z + v0.w) + (v1.x + v1.y + v1.z + v1.w)
          + (v2.x + v2.y + v2.z + v2.w) + (v3.x + v3.y + v3.z + v3.w);
  #pragma unroll
  for (int o = 32; o > 0; o >>= 1) s += __shfl_down(s, o, 64);
  if (lane == 0) pooled[row] = s * (1.0f / 1024.0f);
}

// ------------------------------------------------------------------
// 3) SE
// ------------------------------------------------------------------
__global__ __launch_bounds__(256) void k_se(const float* __restrict__ pooled,
    const float* __restrict__ Wse1, const float* __restrict__ bse1,
    const float* __restrict__ Wse2, const float* __restrict__ bse2,
    float* __restrict__ cw){
  __shared__ float pl[512];
  __shared__ float h1[32];
  int b = blockIdx.x, t = threadIdx.x;
  pl[t] = pooled[b * 512 + t];
  pl[t + 256] = pooled[b * 512 + t + 256];
  __syncthreads();
  if (t < 32){
    float acc = bse1[t];
    const float* w = Wse1 + t * 512;
    for (int c = 0; c < 512; c++) acc = fmaf(pl[c], w[c], acc);
    h1[t] = fmaxf(acc, 0.0f);
  }
  __syncthreads();
  for (int c = t; c < 512; c += 256){
    float acc = bse2[c];
    const float* w = Wse2 + c * 32;
    #pragma unroll
    for (int j = 0; j < 32; j++) acc = fmaf(h1[j], w[j], acc);
    cw[b * 512 + c] = 1.0f / (1.0f + expf(-acc));
  }
}

// ------------------------------------------------------------------
// 4) spatial gate (f32 — mask threshold precision-critical)
// ------------------------------------------------------------------
__global__ __launch_bounds__(256) void k_sp(const float* __restrict__ x,
    const float* __restrict__ Wsp, const float* __restrict__ bsp, float* __restrict__ mbuf){
  __shared__ float wsh[4096];
  __shared__ float part[4][512];
  int t = threadIdx.x;
  for (int i = t; i < 4096; i += 256) wsh[i] = Wsp[i];
  __syncthreads();
  int b = blockIdx.x >> 4, n0 = (blockIdx.x & 15) << 6;
  int px = t & 63, cq = t >> 6;
  const float* xp = x + ((size_t)b << 19) + ((size_t)(cq * 128) << 10) + n0 + px;
  float acc[8] = {0,0,0,0,0,0,0,0};
  for (int c = 0; c < 128; c++){
    float xv = xp[(size_t)c << 10];
    #pragma unroll
    for (int h = 0; h < 8; h++) acc[h] = fmaf(xv, wsh[(h << 9) + cq * 128 + c], acc[h]);
  }
  #pragma unroll
  for (int h = 0; h < 8; h++) part[cq][(h << 6) + px] = acc[h];
  __syncthreads();
  for (int i = t; i < 512; i += 256){
    int h = i >> 6, p = i & 63;
    float s = part[0][i] + part[1][i] + part[2][i] + part[3][i] + bsp[h];
    mbuf[(((size_t)(b * 8 + h)) << 10) + n0 + p] = 1.0f / (1.0f + expf(-s));
  }
}

// ------------------------------------------------------------------
// 5) adaptive pool 7x7, threshold, upsample -> bneg (B,8,N) in {0,-1e9}
// ------------------------------------------------------------------
__global__ void k_mask(const float* __restrict__ mbuf, float* __restrict__ bneg){
  __shared__ float sm[1024];
  __shared__ float mg[49];
  int bh = blockIdx.x, t = threadIdx.x;
  const float* mp = mbuf + ((size_t)bh << 10);
  for (int i = t; i < 1024; i += 64) sm[i] = mp[i];
  __syncthreads();
  if (t < 49){
    int ci = t / 7, cj = t % 7;
    int r0 = (ci * 32) / 7, r1 = ((ci + 1) * 32 + 6) / 7;
    int c0 = (cj * 32) / 7, c1 = ((cj + 1) * 32 + 6) / 7;
    float acc = 0.0f;
    for (int cc = c0; cc < c1; cc++){
      float rs = 0.0f;
      for (int rr = r0; rr < r1; rr++) rs += sm[rr * 32 + cc];
      acc += rs / (float)(r1 - r0);
    }
    float v = acc / (float)(c1 - c0);
    mg[t] = (v > 0.5f) ? 1.0f : 0.0f;
  }
  __syncthreads();
  for (int i = t; i < 1024; i += 64){
    int r = i >> 5, c = i & 31;
    float m = mg[((r * 7) >> 5) * 7 + ((c * 7) >> 5)];
    bneg[((size_t)bh << 10) + i] = (m > 0.5f) ? 0.0f : -1e9f;
  }
}

// ------------------------------------------------------------------
// 6) xf[b][n][c] = bf16( x[b][c][n] * cw[b][c] )
// ------------------------------------------------------------------
__global__ __launch_bounds__(256) void k_xf(const float* __restrict__ x,
    const float* __restrict__ cw, u16* __restrict__ xfB){
  __shared__ float tile[64][65];
  int bid = blockIdx.x;
  int b = bid >> 7, c0 = ((bid >> 4) & 7) << 6, n0 = (bid & 15) << 6;
  int t = threadIdx.x;
  {
    int cl = t >> 2, nc = (t & 3) << 4;
    const float* xp = x + ((size_t)(b * 512 + c0 + cl) << 10) + n0 + nc;
    float cwv = cw[b * 512 + c0 + cl];
    #pragma unroll
    for (int i = 0; i < 16; i += 4){
      float4 v = *(const float4*)(xp + i);
      tile[cl][nc + i + 0] = v.x * cwv;
      tile[cl][nc + i + 1] = v.y * cwv;
      tile[cl][nc + i + 2] = v.z * cwv;
      tile[cl][nc + i + 3] = v.w * cwv;
    }
  }
  __syncthreads();
  {
    int nl = t >> 2, cc = (t & 3) << 4;
    u16* op = xfB + ((size_t)(b * 1024 + n0 + nl) << 9) + c0 + cc;
    us8 o0, o1;
    #pragma unroll
    for (int i = 0; i < 8; i++)  o0[i] = f2b(tile[cc + i][nl]);
    #pragma unroll
    for (int i = 0; i < 8; i++)  o1[i] = f2b(tile[cc + 8 + i][nl]);
    *(us8*)op = o0;
    *(us8*)(op + 8) = o1;
  }
}

// ------------------------------------------------------------------
// 7/9) bf16 MFMA GEMM — round-2 proven K-loop (BK=32, pitch 40, 20.5KB LDS)
//   + coalesced LDS epilogue in two 64-row passes (C_lds overlays As/Bs).
//   Q/K: swapped mfma (tokens on lane&15) -> token-row C_lds -> us8 stores.
//   V: unswapped -> channel-row C_lds, slot-permuted token cols -> us8.
//   MODE 1 (Wo): swapped, direct float4 stores (full 64B lines).
// ------------------------------------------------------------------
template<int MODE>
DI void gemm_body(const u16* __restrict__ A, const u16* __restrict__ Bw,
    const float* __restrict__ b0, const float* __restrict__ b1, const float* __restrict__ b2,
    u16* __restrict__ outQ, u16* __restrict__ outK, u16* __restrict__ outV, float* __restrict__ outF){
  __shared__ __align__(16) u16 smem[10240];   // As+Bs = 20480B; epilogue overlay 64x136 = 17408B
  u16* As = smem;            // 128 x 40
  u16* Bs = smem + 5120;     // 128 x 40
  int m0 = blockIdx.x * 128, n0 = blockIdx.y * 128;
  bool vblk = (MODE == 0) && (n0 >= 1024);
  int t = threadIdx.x, lane = t & 63, w = t >> 6;
  int wr = w >> 1, wc = w & 1;
  int g = lane >> 4, li = lane & 15;
  f32x4 acc[4][4];
  #pragma unroll
  for (int mt = 0; mt < 4; mt++)
    #pragma unroll
    for (int nt = 0; nt < 4; nt++) acc[mt][nt] = (f32x4){0.f, 0.f, 0.f, 0.f};

  int srow = t >> 1, scol = (t & 1) << 4;
  const u16* ap = A  + (size_t)(m0 + srow) * 512 + scol;
  const u16* bp = Bw + (size_t)(n0 + srow) * 512 + scol;

  for (int k0 = 0; k0 < 512; k0 += 32){
    uint4 av0 = *(const uint4*)(ap + k0);
    uint4 av1 = *(const uint4*)(ap + k0 + 8);
    uint4 bv0 = *(const uint4*)(bp + k0);
    uint4 bv1 = *(const uint4*)(bp + k0 + 8);
    *(uint4*)&As[srow * 40 + scol]     = av0;
    *(uint4*)&As[srow * 40 + scol + 8] = av1;
    *(uint4*)&Bs[srow * 40 + scol]     = bv0;
    *(uint4*)&Bs[srow * 40 + scol + 8] = bv1;
    __syncthreads();
    bf16x8 afr[4], bfr[4];
    #pragma unroll
    for (int mt = 0; mt < 4; mt++)
      afr[mt] = *(bf16x8*)&As[(wr * 64 + mt * 16 + li) * 40 + (g << 3)];
    #pragma unroll
    for (int nt = 0; nt < 4; nt++)
      bfr[nt] = *(bf16x8*)&Bs[(wc * 64 + nt * 16 + li) * 40 + (g << 3)];
    if (vblk){
      #pragma unroll
      for (int mt = 0; mt < 4; mt++)
        #pragma unroll
        for (int nt = 0; nt < 4; nt++)
          acc[mt][nt] = __builtin_amdgcn_mfma_f32_16x16x32_bf16(afr[mt], bfr[nt], acc[mt][nt], 0, 0, 0);
    } else {
      #pragma unroll
      for (int mt = 0; mt < 4; mt++)
        #pragma unroll
        for (int nt = 0; nt < 4; nt++)
          acc[mt][nt] = __builtin_amdgcn_mfma_f32_16x16x32_bf16(bfr[nt], afr[mt], acc[mt][nt], 0, 0, 0);
    }
    __syncthreads();
  }

  if (MODE == 1){
    // swapped: lane li = token, reg quartet (g*4+j) = contiguous channels.
    #pragma unroll
    for (int mt = 0; mt < 4; mt++){
      #pragma unroll
      for (int nt = 0; nt < 4; nt++){
        int m = m0 + wr * 64 + mt * 16 + li;
        int obase = n0 + wc * 64 + nt * 16 + (g << 2);
        float4 bias4 = *(const float4*)&b0[obase];
        float4 vo = { acc[mt][nt][0] + bias4.x, acc[mt][nt][1] + bias4.y,
                      acc[mt][nt][2] + bias4.z, acc[mt][nt][3] + bias4.w };
        *(float4*)&outF[(size_t)m * 512 + obase] = vo;
      }
    }
    return;
  }

  // ---- MODE 0: two-pass LDS-staged coalesced epilogue
  u16* Cl = smem;   // 64 x 136
  const float* bb = vblk ? b2 : ((n0 >> 9) ? b1 : b0);
  #pragma unroll
  for (int p = 0; p < 2; p++){
    __syncthreads();
    if (vblk){
      // unswapped: lane li = channel-in-16, reg (4g+j) = token.
      // pass p handles channel half wc==p; C_lds row = nt*16+li (channel),
      // col = permuted token (flash slot-perm folded in).
      if (wc == p){
        #pragma unroll
        for (int mt = 0; mt < 4; mt++){
          #pragma unroll
          for (int nt = 0; nt < 4; nt++){
            int row = nt * 16 + li;
            float bias = bb[(n0 & 511) + p * 64 + row];
            int col = wr * 64 + ((mt >> 1) << 5) + (g << 3) + ((mt & 1) << 2);
            us4 pk;
            #pragma unroll
            for (int j = 0; j < 4; j++) pk[j] = f2b(acc[mt][nt][j] + bias);
            *(us4*)&Cl[row * 136 + col] = pk;
          }
        }
      }
    } else {
      // swapped: lane li = token-in-16, reg (4g+j) = channel.
      // pass p handles token half wr==p; C_lds row = mt*16+li (token).
      if (wr == p){
        #pragma unroll
        for (int mt = 0; mt < 4; mt++){
          #pragma unroll
          for (int nt = 0; nt < 4; nt++){
            int row = mt * 16 + li;
            int ob = wc * 64 + nt * 16 + (g << 2);
            float4 bias4 = *(const float4*)&bb[(n0 & 511) + ob];
            float bk4[4] = {bias4.x, bias4.y, bias4.z, bias4.w};
            us4 pk;
            #pragma unroll
            for (int j = 0; j < 4; j++) pk[j] = f2b(acc[mt][nt][j] + bk4[j]);
            *(us4*)&Cl[row * 136 + ob] = pk;
          }
        }
      }
    }
    __syncthreads();
    int r = t >> 4, ol = (t & 15) << 3;
    if (vblk){
      // rows = channels (2 heads per pass-half), cols = 128 permuted tokens
      int b = m0 >> 10, nt0 = m0 & 1023;
      #pragma unroll
      for (int pp = 0; pp < 4; pp++){
        int rr = pp * 16 + r;
        int c = (n0 & 511) + p * 64 + rr, h = c >> 6, dv = c & 63;
        us8 v = *(us8*)&Cl[rr * 136 + ol];
        *(us8*)&outV[(((size_t)(b * 8 + h)) << 16) + ((size_t)dv << 10) + nt0 + ol] = v;
      }
    } else {
      // rows = tokens, 256B row = two 128B full-line chunks (2 heads)
      u16* base = (n0 >> 9) ? outK : outQ;
      #pragma unroll
      for (int pp = 0; pp < 4; pp++){
        int rr = pp * 16 + r;
        int m = m0 + p * 64 + rr, b = m >> 10, n = m & 1023;
        int c = (n0 & 511) + ol, h = c >> 6, dv = c & 63;
        us8 v = *(us8*)&Cl[rr * 136 + ol];
        *(us8*)&base[(((size_t)(b * 8 + h)) << 16) + ((size_t)n << 6) + dv] = v;
      }
    }
  }
}

__global__ __launch_bounds__(256) void k_gemm_qkv(const u16* __restrict__ A, const u16* __restrict__ Bw,
    const float* __restrict__ b0, const float* __restrict__ b1, const float* __restrict__ b2,
    u16* __restrict__ outQ, u16* __restrict__ outK, u16* __restrict__ outV){
  gemm_body<0>(A, Bw, b0, b1, b2, outQ, outK, outV, nullptr);
}

__global__ __launch_bounds__(256) void k_gemm_o(const u16* __restrict__ A, const u16* __restrict__ Bw,
    const float* __restrict__ b0, float* __restrict__ outF){
  gemm_body<1>(A, Bw, b0, nullptr, nullptr, nullptr, nullptr, nullptr, outF);
}

// ------------------------------------------------------------------
// 8) flash attention, swapped-operand form + XCD swizzle + defer-max.
// ------------------------------------------------------------------
__global__ __launch_bounds__(256) void k_flash(const u16* __restrict__ Q, const u16* __restrict__ K,
    const u16* __restrict__ Vt, const float* __restrict__ bneg, u16* __restrict__ attnB){
  __shared__ __align__(16) u16 Ks[64 * 72];
  __shared__ __align__(16) u16 Vts[64 * 72];
  __shared__ float mks[64];
  int hw = blockIdx.x;
  int bid = ((hw & 7) << 7) + (hw >> 3);     // XCD swizzle: all 16 q-tiles of a bh on one XCD
  int bh = bid >> 4, q0 = (bid & 15) << 6;
  int t = threadIdx.x, lane = t & 63, w = t >> 6;
  int g = lane >> 4, li = lane & 15;

  const u16* Kp = K  + ((size_t)bh << 16);
  const u16* Vp = Vt + ((size_t)bh << 16);
  const float* bp = bneg + ((size_t)bh << 10);

  bf16x8 qfr0, qfr1;
  {
    const u16* qrow = Q + ((size_t)bh << 16) + ((size_t)(q0 + w * 16 + li) << 6);
    qfr0 = *(const bf16x8*)(qrow + g * 8);
    qfr1 = *(const bf16x8*)(qrow + 32 + g * 8);
  }
  float bnq = bp[q0 + w * 16 + li];

  f32x4 oacc[4];
  #pragma unroll
  for (int dt = 0; dt < 4; dt++) oacc[dt] = (f32x4){0.f, 0.f, 0.f, 0.f};
  float mrun = -INFINITY, lrun = 0.0f;

  int sr = t >> 2, sc = (t & 3) << 4;
  const u16* kg = Kp + ((size_t)sr << 6) + sc;
  const u16* vg = Vp + ((size_t)sr << 10) + sc;
  uint4 kr0, kr1, vr0, vr1;
  float mr = 0.0f;
  kr0 = *(const uint4*)(kg);
  kr1 = *(const uint4*)(kg + 8);
  vr0 = *(const uint4*)(vg);
  vr1 = *(const uint4*)(vg + 8);
  if (t < 64) mr = bp[t];

  for (int kt = 0; kt < 16; kt++){
    __syncthreads();
    *(uint4*)&Ks[sr * 72 + sc]      = kr0;
    *(uint4*)&Ks[sr * 72 + sc + 8]  = kr1;
    *(uint4*)&Vts[sr * 72 + sc]     = vr0;
    *(uint4*)&Vts[sr * 72 + sc + 8] = vr1;
    if (t < 64) mks[t] = mr;
    if (kt < 15){
      kr0 = *(const uint4*)(kg + (kt + 1) * 4096);
      kr1 = *(const uint4*)(kg + (kt + 1) * 4096 + 8);
      vr0 = *(const uint4*)(vg + (kt + 1) * 64);
      vr1 = *(const uint4*)(vg + (kt + 1) * 64 + 8);
      if (t < 64) mr = bp[(kt + 1) * 64 + t];
    }
    __syncthreads();

    // S^T = K Q^T : sacc[mt][j] = S[key=mt*16+4g+j][q=li]
    f32x4 sacc[4];
    #pragma unroll
    for (int mt = 0; mt < 4; mt++) sacc[mt] = (f32x4){0.f, 0.f, 0.f, 0.f};
    #pragma unroll
    for (int mt = 0; mt < 4; mt++){
      bf16x8 kfr0 = *(bf16x8*)&Ks[(mt * 16 + li) * 72 + g * 8];
      bf16x8 kfr1 = *(bf16x8*)&Ks[(mt * 16 + li) * 72 + 32 + g * 8];
      sacc[mt] = __builtin_amdgcn_mfma_f32_16x16x32_bf16(kfr0, qfr0, sacc[mt], 0, 0, 0);
      sacc[mt] = __builtin_amdgcn_mfma_f32_16x16x32_bf16(kfr1, qfr1, sacc[mt], 0, 0, 0);
    }

    float tmax = -INFINITY;
    #pragma unroll
    for (int mt = 0; mt < 4; mt++){
      float4 bk = *(const float4*)&mks[mt * 16 + g * 4];
      float bkk[4] = {bk.x, bk.y, bk.z, bk.w};
      #pragma unroll
      for (int j = 0; j < 4; j++){
        float s = sacc[mt][j] * 0.125f + fminf(bkk[j], bnq);
        sacc[mt][j] = s;
        tmax = fmaxf(tmax, s);
      }
    }
    tmax = fmaxf(tmax, __shfl_xor(tmax, 16, 64));
    tmax = fmaxf(tmax, __shfl_xor(tmax, 32, 64));

    // defer-max (T13)
    if (!__all(tmax <= mrun + 8.0f)){
      float mnew = fmaxf(mrun, tmax);
      float scl = __expf(mrun - mnew);
      mrun = mnew;
      lrun *= scl;
      #pragma unroll
      for (int dt = 0; dt < 4; dt++)
        #pragma unroll
        for (int j = 0; j < 4; j++) oacc[dt][j] *= scl;
    }

    float rsum = 0.0f;
    #pragma unroll
    for (int mt = 0; mt < 4; mt++)
      #pragma unroll
      for (int j = 0; j < 4; j++){
        float p = __expf(sacc[mt][j] - mrun);
        sacc[mt][j] = p;
        rsum += p;
      }
    rsum += __shfl_xor(rsum, 16, 64);
    rsum += __shfl_xor(rsum, 32, 64);
    lrun += rsum;

    bf16x8 pfr0, pfr1;
    #pragma unroll
    for (int e = 0; e < 4; e++){
      pfr0[e]     = (short)f2b(sacc[0][e]);
      pfr0[4 + e] = (short)f2b(sacc[1][e]);
      pfr1[e]     = (short)f2b(sacc[2][e]);
      pfr1[4 + e] = (short)f2b(sacc[3][e]);
    }
    #pragma unroll
    for (int dt = 0; dt < 4; dt++){
      bf16x8 vfr0 = *(bf16x8*)&Vts[(dt * 16 + li) * 72 + g * 8];
      bf16x8 vfr1 = *(bf16x8*)&Vts[(dt * 16 + li) * 72 + 32 + g * 8];
      oacc[dt] = __builtin_amdgcn_mfma_f32_16x16x32_bf16(vfr0, pfr0, oacc[dt], 0, 0, 0);
      oacc[dt] = __builtin_amdgcn_mfma_f32_16x16x32_bf16(vfr1, pfr1, oacc[dt], 0, 0, 0);
    }
  }

  float inv = 1.0f / lrun;
  int b = bh >> 3, h = bh & 7;
  u16* op = attnB + (((size_t)(b * 1024 + q0 + w * 16 + li)) << 9) + h * 64 + g * 4;
  #pragma unroll
  for (int dt = 0; dt < 4; dt++){
    us4 pk;
    #pragma unroll
    for (int j = 0; j < 4; j++) pk[j] = f2b(oacc[dt][j] * inv);
    *(us4*)(op + dt * 16) = pk;
  }
}

// ------------------------------------------------------------------
// 10) LN over C + transpose to (B,C,N)
// ------------------------------------------------------------------
__global__ __launch_bounds__(256) void k_ln(const u16* __restrict__ xfB, const float* __restrict__ attnO,
    const float* __restrict__ gamma, const float* __restrict__ beta, float* __restrict__ out){
  __shared__ float mu_s[64], rs_s[64];
  __shared__ float tile[64][65];
  int b = blockIdx.x >> 4, n0 = (blockIdx.x & 15) << 6;
  int t = threadIdx.x, w = t >> 6, lane = t & 63;

  for (int r = w * 16; r < w * 16 + 16; r++){
    size_t rb = ((size_t)(b * 1024 + n0 + r)) << 9;
    const float* ap = attnO + rb + lane * 8;
    const u16*  xp = xfB + rb + lane * 8;
    float4 a0 = *(const float4*)ap;
    float4 a1 = *(const float4*)(ap + 4);
    union { uint4 v; u16 u[8]; } xv; xv.v = *(const uint4*)xp;
    float v0 = a0.x + b2f(xv.u[0]), v1 = a0.y + b2f(xv.u[1]);
    float v2 = a0.z + b2f(xv.u[2]), v3 = a0.w + b2f(xv.u[3]);
    float v4 = a1.x + b2f(xv.u[4]), v5 = a1.y + b2f(xv.u[5]);
    float v6 = a1.z + b2f(xv.u[6]), v7 = a1.w + b2f(xv.u[7]);
    float s  = v0 + v1 + v2 + v3 + v4 + v5 + v6 + v7;
    float s2 = v0*v0 + v1*v1 + v2*v2 + v3*v3 + v4*v4 + v5*v5 + v6*v6 + v7*v7;
    #pragma unroll
    for (int o = 32; o > 0; o >>= 1){ s += __shfl_xor(s, o, 64); s2 += __shfl_xor(s2, o, 64); }
    if (lane == 0){
      float mu = s * (1.0f / 512.0f);
      float var = s2 * (1.0f / 512.0f) - mu * mu;
      mu_s[r] = mu;
      rs_s[r] = 1.0f / sqrtf(var + 1e-5f);
    }
  }
  __syncthreads();

  for (int ch = 0; ch < 8; ch++){
    int c0 = ch * 64;
    {
      int r = t >> 2, cp = (t & 3) << 4;
      size_t rb = (((size_t)(b * 1024 + n0 + r)) << 9) + c0 + cp;
      float mu = mu_s[r], rstd = rs_s[r];
      #pragma unroll
      for (int i2 = 0; i2 < 2; i2++){
        float4 a0 = *(const float4*)(attnO + rb + i2 * 8);
        float4 a1 = *(const float4*)(attnO + rb + i2 * 8 + 4);
        union { uint4 v; u16 u[8]; } xv; xv.v = *(const uint4*)(xfB + rb + i2 * 8);
        float vv[8] = { a0.x + b2f(xv.u[0]), a0.y + b2f(xv.u[1]), a0.z + b2f(xv.u[2]), a0.w + b2f(xv.u[3]),
                        a1.x + b2f(xv.u[4]), a1.y + b2f(xv.u[5]), a1.z + b2f(xv.u[6]), a1.w + b2f(xv.u[7]) };
        #pragma unroll
        for (int i = 0; i < 8; i++){
          int c = c0 + cp + i2 * 8 + i;
          tile[r][cp + i2 * 8 + i] = (vv[i] - mu) * rstd * gamma[c] + beta[c];
        }
      }
    }
    __syncthreads();
    {
      int cl = t >> 2, np_ = (t & 3) << 4;
      float* op = out + (((size_t)(b * 512 + c0 + cl)) << 10) + n0 + np_;
      #pragma unroll
      for (int i = 0; i < 16; i += 4){
        float4 vo = { tile[np_ + i][cl], tile[np_ + i + 1][cl], tile[np_ + i + 2][cl], tile[np_ + i + 3][cl] };
        *(float4*)(op + i) = vo;
      }
    }
    __syncthreads();
  }
}

// ------------------------------------------------------------------
extern "C" void kernel_launch(void* const* d_in, const int* in_sizes, int n_in,
                              void* d_out, int out_size, void* d_ws, size_t ws_size,
                              hipStream_t stream){
  (void)in_sizes; (void)n_in; (void)out_size; (void)ws_size;
  const float* x    = (const float*)d_in[0];
  const float* Wq   = (const float*)d_in[1];
  const float* bq   = (const float*)d_in[2];
  const float* Wk   = (const float*)d_in[3];
  const float* bk   = (const float*)d_in[4];
  const float* Wv   = (const float*)d_in[5];
  const float* bv   = (const float*)d_in[6];
  const float* Wo   = (const float*)d_in[7];
  const float* bo   = (const float*)d_in[8];
  const float* Wsp  = (const float*)d_in[9];
  const float* bsp  = (const float*)d_in[10];
  const float* Wse1 = (const float*)d_in[11];
  const float* bse1 = (const float*)d_in[12];
  const float* Wse2 = (const float*)d_in[13];
  const float* bse2 = (const float*)d_in[14];
  const float* gamma= (const float*)d_in[15];
  const float* beta = (const float*)d_in[16];
  float* out = (float*)d_out;

  char* ws = (char*)d_ws;
  size_t off = 0;
  auto alloc = [&](size_t bytes) -> void* {
    void* p = ws + off;
    off += (bytes + 255) & ~(size_t)255;
    return p;
  };
  u16*   WB     = (u16*)  alloc(1536 * 512 * 2);
  u16*   WoB    = (u16*)  alloc(512 * 512 * 2);
  float* pooled = (float*)alloc(4096 * 4);
  float* cw     = (float*)alloc(4096 * 4);
  float* mbuf   = (float*)alloc(65536 * 4);
  float* bneg   = (float*)alloc(65536 * 4);
  u16*   xfB    = (u16*)  alloc((size_t)8192 * 512 * 2);
  u16*   Qb     = (u16*)  alloc(8388608);
  u16*   Kb     = (u16*)  alloc(8388608);
  u16*   VtG    = (u16*)  alloc(8388608);
  u16*   attnB  = (u16*)  alloc(8388608);
  float* attnO  = (float*)Qb;   // alias Q+K after flash

  k_cvt   <<<dim3(1024), dim3(256), 0, stream>>>(Wq, Wk, Wv, Wo, WB, WoB);
  k_pooled<<<dim3(1024), dim3(256), 0, stream>>>(x, pooled);
  k_se    <<<dim3(8),    dim3(256), 0, stream>>>(pooled, Wse1, bse1, Wse2, bse2, cw);
  k_sp    <<<dim3(128),  dim3(256), 0, stream>>>(x, Wsp, bsp, mbuf);
  k_mask  <<<dim3(64),   dim3(64),  0, stream>>>(mbuf, bneg);
  k_xf    <<<dim3(1024), dim3(256), 0, stream>>>(x, cw, xfB);
  k_gemm_qkv<<<dim3(64, 12), dim3(256), 0, stream>>>(xfB, WB, bq, bk, bv, Qb, Kb, VtG);
  k_flash <<<dim3(1024), dim3(256), 0, stream>>>(Qb, Kb, VtG, bneg, attnB);
  k_gemm_o<<<dim3(64, 4), dim3(256), 0, stream>>>(attnB, WoB, bo, attnO);
  k_ln    <<<dim3(128),  dim3(256), 0, stream>>>(xfB, attnO, gamma, beta, out);
}

// Round 8
// 147.561 us; speedup vs baseline: 1.4228x; 1.1476x over previous
//
#include <hip/hip_runtime.h>
#include <hip/hip_bf16.h>
#include <math.h>

typedef unsigned short u16;
typedef unsigned int u32;
typedef __attribute__((ext_vector_type(4))) float f32x4;
typedef __attribute__((ext_vector_type(8))) short bf16x8;
typedef __attribute__((ext_vector_type(4))) unsigned short us4;
typedef __attribute__((ext_vector_type(8))) unsigned short us8;

#define DI __device__ __forceinline__

DI u16 f2b(float x){ __hip_bfloat16 h = __float2bfloat16(x); return *reinterpret_cast<u16*>(&h); }
DI float b2f(u16 u){ union { float f; u32 i; } v; v.i = ((u32)u) << 16; return v.f; }

// direct global->LDS DMA, 16B per lane; LDS dest = wave-uniform base + lane*16
DI void gload16(const void* g, void* l){
  __builtin_amdgcn_global_load_lds((const __attribute__((address_space(1))) void*)g,
                                   (__attribute__((address_space(3))) void*)l, 16, 0, 0);
}

// ------------------------------------------------------------------
// 1) weights -> bf16. WB = [Wq;Wk;Wv] (1536x512), WoB = Wo (512x512)
// ------------------------------------------------------------------
__global__ void k_cvt(const float* __restrict__ Wq, const float* __restrict__ Wk,
                      const float* __restrict__ Wv, const float* __restrict__ Wo,
                      u16* __restrict__ WB, u16* __restrict__ WoB){
  int i = blockIdx.x * 256 + threadIdx.x;
  WB[i]          = f2b(Wq[i]);
  WB[262144 + i] = f2b(Wk[i]);
  WB[524288 + i] = f2b(Wv[i]);
  WoB[i]         = f2b(Wo[i]);
}

// ------------------------------------------------------------------
// 2) pooled[b][c] = mean_n x[b][c][n]
// ------------------------------------------------------------------
__global__ __launch_bounds__(256) void k_pooled(const float* __restrict__ x, float* __restrict__ pooled){
  int row  = blockIdx.x * 4 + (threadIdx.x >> 6);
  int lane = threadIdx.x & 63;
  const float4* p = (const float4*)(x + ((size_t)row << 10));
  float4 v0 = p[lane], v1 = p[lane + 64], v2 = p[lane + 128], v3 = p[lane + 192];
  float s = (v0.x + v0.y + v0.z + v0.w) + (v1.x + v1.y + v1.z + v1.w)
          + (v2.x + v2.y + v2.z + v2.w) + (v3.x + v3.y + v3.z + v3.w);
  #pragma unroll
  for (int o = 32; o > 0; o >>= 1) s += __shfl_down(s, o, 64);
  if (lane == 0) pooled[row] = s * (1.0f / 1024.0f);
}

// ------------------------------------------------------------------
// 3) SE
// ------------------------------------------------------------------
__global__ __launch_bounds__(256) void k_se(const float* __restrict__ pooled,
    const float* __restrict__ Wse1, const float* __restrict__ bse1,
    const float* __restrict__ Wse2, const float* __restrict__ bse2,
    float* __restrict__ cw){
  __shared__ float pl[512];
  __shared__ float h1[32];
  int b = blockIdx.x, t = threadIdx.x;
  pl[t] = pooled[b * 512 + t];
  pl[t + 256] = pooled[b * 512 + t + 256];
  __syncthreads();
  if (t < 32){
    float acc = bse1[t];
    const float* w = Wse1 + t * 512;
    for (int c = 0; c < 512; c++) acc = fmaf(pl[c], w[c], acc);
    h1[t] = fmaxf(acc, 0.0f);
  }
  __syncthreads();
  for (int c = t; c < 512; c += 256){
    float acc = bse2[c];
    const float* w = Wse2 + c * 32;
    #pragma unroll
    for (int j = 0; j < 32; j++) acc = fmaf(h1[j], w[j], acc);
    cw[b * 512 + c] = 1.0f / (1.0f + expf(-acc));
  }
}

// ------------------------------------------------------------------
// 4+6 fused) k_spxf: one pass over x producing
//   mbuf[b][h][n] = sigmoid(sum_c x*Wsp + bsp)   (f32, precision-critical)
//   xfB[b][n][c]  = bf16(x * cw)                 (transpose)
//   grid 256 = 8b x 32 chunks of 32 px, 256 threads
// ------------------------------------------------------------------
__global__ __launch_bounds__(256) void k_spxf(const float* __restrict__ x,
    const float* __restrict__ Wsp, const float* __restrict__ bsp,
    const float* __restrict__ cw, float* __restrict__ mbuf, u16* __restrict__ xfB){
  __shared__ float wsh[4096];        // Wsp[h][c]
  __shared__ float cwl[512];
  __shared__ float tile[64][36];     // raw x chunk [64 c][32 px]
  __shared__ float part[8][256];     // [cg][h*32 + px]
  int t = threadIdx.x;
  int b = blockIdx.x >> 5, n0 = (blockIdx.x & 31) << 5;
  for (int i = t; i < 4096; i += 256) wsh[i] = Wsp[i];
  cwl[t] = cw[b * 512 + t];
  cwl[t + 256] = cw[b * 512 + t + 256];

  int nl = t & 31, cg = t >> 5;
  int lr = t >> 2, lc = (t & 3) << 3;
  float acc[8] = {0,0,0,0,0,0,0,0};

  for (int cb = 0; cb < 8; cb++){
    __syncthreads();   // prev reads done (and wsh/cwl ready on cb=0)
    const float* xp = x + ((size_t)(b * 512 + cb * 64 + lr) << 10) + n0 + lc;
    float4 v0 = *(const float4*)xp;
    float4 v1 = *(const float4*)(xp + 4);
    *(float4*)&tile[lr][lc]     = v0;
    *(float4*)&tile[lr][lc + 4] = v1;
    __syncthreads();
    us8 pk;
    #pragma unroll
    for (int i = 0; i < 8; i++){
      int c = cb * 64 + cg * 8 + i;
      float v = tile[cg * 8 + i][nl];
      pk[i] = f2b(v * cwl[c]);
      #pragma unroll
      for (int h = 0; h < 8; h++) acc[h] = fmaf(v, wsh[(h << 9) + c], acc[h]);
    }
    *(us8*)&xfB[(((size_t)(b * 1024 + n0 + nl)) << 9) + cb * 64 + cg * 8] = pk;
  }
  #pragma unroll
  for (int h = 0; h < 8; h++) part[cg][h * 32 + nl] = acc[h];
  __syncthreads();
  {
    int h = t >> 5, px = t & 31;
    float s = bsp[h];
    #pragma unroll
    for (int g2 = 0; g2 < 8; g2++) s += part[g2][h * 32 + px];
    mbuf[(((size_t)(b * 8 + h)) << 10) + n0 + px] = 1.0f / (1.0f + expf(-s));
  }
}

// ------------------------------------------------------------------
// 5) adaptive pool 7x7, threshold, upsample -> bneg (B,8,N) in {0,-1e9}
// ------------------------------------------------------------------
__global__ void k_mask(const float* __restrict__ mbuf, float* __restrict__ bneg){
  __shared__ float sm[1024];
  __shared__ float mg[49];
  int bh = blockIdx.x, t = threadIdx.x;
  const float* mp = mbuf + ((size_t)bh << 10);
  for (int i = t; i < 1024; i += 64) sm[i] = mp[i];
  __syncthreads();
  if (t < 49){
    int ci = t / 7, cj = t % 7;
    int r0 = (ci * 32) / 7, r1 = ((ci + 1) * 32 + 6) / 7;
    int c0 = (cj * 32) / 7, c1 = ((cj + 1) * 32 + 6) / 7;
    float acc = 0.0f;
    for (int cc = c0; cc < c1; cc++){
      float rs = 0.0f;
      for (int rr = r0; rr < r1; rr++) rs += sm[rr * 32 + cc];
      acc += rs / (float)(r1 - r0);
    }
    float v = acc / (float)(c1 - c0);
    mg[t] = (v > 0.5f) ? 1.0f : 0.0f;
  }
  __syncthreads();
  for (int i = t; i < 1024; i += 64){
    int r = i >> 5, c = i & 31;
    float m = mg[((r * 7) >> 5) * 7 + ((c * 7) >> 5)];
    bneg[((size_t)bh << 10) + i] = (m > 0.5f) ? 0.0f : -1e9f;
  }
}

// ------------------------------------------------------------------
// 7/9) bf16 MFMA GEMM — double-buffered global_load_lds (16B) K-loop,
//   BK=32, one barrier per K-step. LDS linear [128][32] per matrix with
//   chunk-XOR swizzle folded into the pre-swizzled GLOBAL source (m173);
//   ds_read_b128 conflict-free. Coalesced LDS-staged epilogue (proven r6).
// ------------------------------------------------------------------
template<int MODE>
DI void gemm_body(const u16* __restrict__ A, const u16* __restrict__ Bw,
    const float* __restrict__ b0, const float* __restrict__ b1, const float* __restrict__ b2,
    u16* __restrict__ outQ, u16* __restrict__ outK, u16* __restrict__ outV, float* __restrict__ outF){
  __shared__ __align__(16) u16 smem[16384];   // 2 bufs x (A 4096 + B 4096) u16 = 32KB
  int m0 = blockIdx.x * 128, n0 = blockIdx.y * 128;
  bool vblk = (MODE == 0) && (n0 >= 1024);
  int t = threadIdx.x, lane = t & 63, w = t >> 6;
  int wr = w >> 1, wc = w & 1;
  int g = lane >> 4, li = lane & 15;
  f32x4 acc[4][4];
  #pragma unroll
  for (int mt = 0; mt < 4; mt++)
    #pragma unroll
    for (int nt = 0; nt < 4; nt++) acc[mt][nt] = (f32x4){0.f, 0.f, 0.f, 0.f};

  // staging constants: lane covers row rl=l>>2 of a 16-row group; global
  // chunk pre-swizzled so LDS(r, c) holds global chunk c ^ ((r>>1)&3)
  int cof = (((lane & 3) ^ ((lane >> 3) & 3)) << 3);
  int rl = lane >> 2;
  const u16* gA = A  + (size_t)(m0 + w * 32 + rl) * 512 + cof;
  const u16* gB = Bw + (size_t)(n0 + w * 32 + rl) * 512 + cof;
  u16* lA = smem + (w * 32) * 32;          // + buf*8192
  u16* lB = smem + 4096 + (w * 32) * 32;

  #define STAGE(buf, k0)                                              \
    gload16(gA + (k0),            lA + (buf) * 8192);                 \
    gload16(gA + (k0) + 16 * 512, lA + (buf) * 8192 + 512);           \
    gload16(gB + (k0),            lB + (buf) * 8192);                 \
    gload16(gB + (k0) + 16 * 512, lB + (buf) * 8192 + 512);

  STAGE(0, 0);
  __syncthreads();

  int rsw = ((li >> 1) & 3);
  int cA = (g ^ rsw) << 3;
  int cur = 0;
  for (int ks = 0; ks < 16; ks++){
    if (ks < 15){ STAGE(cur ^ 1, (ks + 1) * 32); }
    const u16* Ac = smem + cur * 8192;
    const u16* Bc = smem + cur * 8192 + 4096;
    bf16x8 afr[4], bfr[4];
    #pragma unroll
    for (int mt = 0; mt < 4; mt++)
      afr[mt] = *(const bf16x8*)&Ac[(wr * 64 + mt * 16 + li) * 32 + cA];
    #pragma unroll
    for (int nt = 0; nt < 4; nt++)
      bfr[nt] = *(const bf16x8*)&Bc[(wc * 64 + nt * 16 + li) * 32 + cA];
    if (vblk){
      #pragma unroll
      for (int mt = 0; mt < 4; mt++)
        #pragma unroll
        for (int nt = 0; nt < 4; nt++)
          acc[mt][nt] = __builtin_amdgcn_mfma_f32_16x16x32_bf16(afr[mt], bfr[nt], acc[mt][nt], 0, 0, 0);
    } else {
      #pragma unroll
      for (int mt = 0; mt < 4; mt++)
        #pragma unroll
        for (int nt = 0; nt < 4; nt++)
          acc[mt][nt] = __builtin_amdgcn_mfma_f32_16x16x32_bf16(bfr[nt], afr[mt], acc[mt][nt], 0, 0, 0);
    }
    __syncthreads();   // drains next-buf loads + all reads of cur done
    cur ^= 1;
  }
  #undef STAGE

  if (MODE == 1){
    #pragma unroll
    for (int mt = 0; mt < 4; mt++){
      #pragma unroll
      for (int nt = 0; nt < 4; nt++){
        int m = m0 + wr * 64 + mt * 16 + li;
        int obase = n0 + wc * 64 + nt * 16 + (g << 2);
        float4 bias4 = *(const float4*)&b0[obase];
        float4 vo = { acc[mt][nt][0] + bias4.x, acc[mt][nt][1] + bias4.y,
                      acc[mt][nt][2] + bias4.z, acc[mt][nt][3] + bias4.w };
        *(float4*)&outF[(size_t)m * 512 + obase] = vo;
      }
    }
    return;
  }

  // ---- MODE 0: two-pass LDS-staged coalesced epilogue (proven r6/r7)
  u16* Cl = smem;   // 64 x 136
  const float* bb = vblk ? b2 : ((n0 >> 9) ? b1 : b0);
  #pragma unroll
  for (int p = 0; p < 2; p++){
    __syncthreads();
    if (vblk){
      if (wc == p){
        #pragma unroll
        for (int mt = 0; mt < 4; mt++){
          #pragma unroll
          for (int nt = 0; nt < 4; nt++){
            int row = nt * 16 + li;
            float bias = bb[(n0 & 511) + p * 64 + row];
            int col = wr * 64 + ((mt >> 1) << 5) + (g << 3) + ((mt & 1) << 2);
            us4 pk;
            #pragma unroll
            for (int j = 0; j < 4; j++) pk[j] = f2b(acc[mt][nt][j] + bias);
            *(us4*)&Cl[row * 136 + col] = pk;
          }
        }
      }
    } else {
      if (wr == p){
        #pragma unroll
        for (int mt = 0; mt < 4; mt++){
          #pragma unroll
          for (int nt = 0; nt < 4; nt++){
            int row = mt * 16 + li;
            int ob = wc * 64 + nt * 16 + (g << 2);
            float4 bias4 = *(const float4*)&bb[(n0 & 511) + ob];
            float bk4[4] = {bias4.x, bias4.y, bias4.z, bias4.w};
            us4 pk;
            #pragma unroll
            for (int j = 0; j < 4; j++) pk[j] = f2b(acc[mt][nt][j] + bk4[j]);
            *(us4*)&Cl[row * 136 + ob] = pk;
          }
        }
      }
    }
    __syncthreads();
    int r = t >> 4, ol = (t & 15) << 3;
    if (vblk){
      int b = m0 >> 10, nt0 = m0 & 1023;
      #pragma unroll
      for (int pp = 0; pp < 4; pp++){
        int rr = pp * 16 + r;
        int c = (n0 & 511) + p * 64 + rr, h = c >> 6, dv = c & 63;
        us8 v = *(us8*)&Cl[rr * 136 + ol];
        *(us8*)&outV[(((size_t)(b * 8 + h)) << 16) + ((size_t)dv << 10) + nt0 + ol] = v;
      }
    } else {
      u16* base = (n0 >> 9) ? outK : outQ;
      #pragma unroll
      for (int pp = 0; pp < 4; pp++){
        int rr = pp * 16 + r;
        int m = m0 + p * 64 + rr, b = m >> 10, n = m & 1023;
        int c = (n0 & 511) + ol, h = c >> 6, dv = c & 63;
        us8 v = *(us8*)&Cl[rr * 136 + ol];
        *(us8*)&base[(((size_t)(b * 8 + h)) << 16) + ((size_t)n << 6) + dv] = v;
      }
    }
  }
}

__global__ __launch_bounds__(256) void k_gemm_qkv(const u16* __restrict__ A, const u16* __restrict__ Bw,
    const float* __restrict__ b0, const float* __restrict__ b1, const float* __restrict__ b2,
    u16* __restrict__ outQ, u16* __restrict__ outK, u16* __restrict__ outV){
  gemm_body<0>(A, Bw, b0, b1, b2, outQ, outK, outV, nullptr);
}

__global__ __launch_bounds__(256) void k_gemm_o(const u16* __restrict__ A, const u16* __restrict__ Bw,
    const float* __restrict__ b0, float* __restrict__ outF){
  gemm_body<1>(A, Bw, b0, nullptr, nullptr, nullptr, nullptr, nullptr, outF);
}

// ------------------------------------------------------------------
// 8) flash attention, swapped-operand form + XCD swizzle + defer-max
//    + setprio around MFMA clusters (T5).
// ------------------------------------------------------------------
__global__ __launch_bounds__(256) void k_flash(const u16* __restrict__ Q, const u16* __restrict__ K,
    const u16* __restrict__ Vt, const float* __restrict__ bneg, u16* __restrict__ attnB){
  __shared__ __align__(16) u16 Ks[64 * 72];
  __shared__ __align__(16) u16 Vts[64 * 72];
  __shared__ float mks[64];
  int hw = blockIdx.x;
  int bid = ((hw & 7) << 7) + (hw >> 3);
  int bh = bid >> 4, q0 = (bid & 15) << 6;
  int t = threadIdx.x, lane = t & 63, w = t >> 6;
  int g = lane >> 4, li = lane & 15;

  const u16* Kp = K  + ((size_t)bh << 16);
  const u16* Vp = Vt + ((size_t)bh << 16);
  const float* bp = bneg + ((size_t)bh << 10);

  bf16x8 qfr0, qfr1;
  {
    const u16* qrow = Q + ((size_t)bh << 16) + ((size_t)(q0 + w * 16 + li) << 6);
    qfr0 = *(const bf16x8*)(qrow + g * 8);
    qfr1 = *(const bf16x8*)(qrow + 32 + g * 8);
  }
  float bnq = bp[q0 + w * 16 + li];

  f32x4 oacc[4];
  #pragma unroll
  for (int dt = 0; dt < 4; dt++) oacc[dt] = (f32x4){0.f, 0.f, 0.f, 0.f};
  float mrun = -INFINITY, lrun = 0.0f;

  int sr = t >> 2, sc = (t & 3) << 4;
  const u16* kg = Kp + ((size_t)sr << 6) + sc;
  const u16* vg = Vp + ((size_t)sr << 10) + sc;
  uint4 kr0, kr1, vr0, vr1;
  float mr = 0.0f;
  kr0 = *(const uint4*)(kg);
  kr1 = *(const uint4*)(kg + 8);
  vr0 = *(const uint4*)(vg);
  vr1 = *(const uint4*)(vg + 8);
  if (t < 64) mr = bp[t];

  for (int kt = 0; kt < 16; kt++){
    __syncthreads();
    *(uint4*)&Ks[sr * 72 + sc]      = kr0;
    *(uint4*)&Ks[sr * 72 + sc + 8]  = kr1;
    *(uint4*)&Vts[sr * 72 + sc]     = vr0;
    *(uint4*)&Vts[sr * 72 + sc + 8] = vr1;
    if (t < 64) mks[t] = mr;
    if (kt < 15){
      kr0 = *(const uint4*)(kg + (kt + 1) * 4096);
      kr1 = *(const uint4*)(kg + (kt + 1) * 4096 + 8);
      vr0 = *(const uint4*)(vg + (kt + 1) * 64);
      vr1 = *(const uint4*)(vg + (kt + 1) * 64 + 8);
      if (t < 64) mr = bp[(kt + 1) * 64 + t];
    }
    __syncthreads();

    f32x4 sacc[4];
    #pragma unroll
    for (int mt = 0; mt < 4; mt++) sacc[mt] = (f32x4){0.f, 0.f, 0.f, 0.f};
    __builtin_amdgcn_s_setprio(1);
    #pragma unroll
    for (int mt = 0; mt < 4; mt++){
      bf16x8 kfr0 = *(bf16x8*)&Ks[(mt * 16 + li) * 72 + g * 8];
      bf16x8 kfr1 = *(bf16x8*)&Ks[(mt * 16 + li) * 72 + 32 + g * 8];
      sacc[mt] = __builtin_amdgcn_mfma_f32_16x16x32_bf16(kfr0, qfr0, sacc[mt], 0, 0, 0);
      sacc[mt] = __builtin_amdgcn_mfma_f32_16x16x32_bf16(kfr1, qfr1, sacc[mt], 0, 0, 0);
    }
    __builtin_amdgcn_s_setprio(0);

    float tmax = -INFINITY;
    #pragma unroll
    for (int mt = 0; mt < 4; mt++){
      float4 bk = *(const float4*)&mks[mt * 16 + g * 4];
      float bkk[4] = {bk.x, bk.y, bk.z, bk.w};
      #pragma unroll
      for (int j = 0; j < 4; j++){
        float s = sacc[mt][j] * 0.125f + fminf(bkk[j], bnq);
        sacc[mt][j] = s;
        tmax = fmaxf(tmax, s);
      }
    }
    tmax = fmaxf(tmax, __shfl_xor(tmax, 16, 64));
    tmax = fmaxf(tmax, __shfl_xor(tmax, 32, 64));

    if (!__all(tmax <= mrun + 8.0f)){
      float mnew = fmaxf(mrun, tmax);
      float scl = __expf(mrun - mnew);
      mrun = mnew;
      lrun *= scl;
      #pragma unroll
      for (int dt = 0; dt < 4; dt++)
        #pragma unroll
        for (int j = 0; j < 4; j++) oacc[dt][j] *= scl;
    }

    float rsum = 0.0f;
    #pragma unroll
    for (int mt = 0; mt < 4; mt++)
      #pragma unroll
      for (int j = 0; j < 4; j++){
        float p = __expf(sacc[mt][j] - mrun);
        sacc[mt][j] = p;
        rsum += p;
      }
    rsum += __shfl_xor(rsum, 16, 64);
    rsum += __shfl_xor(rsum, 32, 64);
    lrun += rsum;

    bf16x8 pfr0, pfr1;
    #pragma unroll
    for (int e = 0; e < 4; e++){
      pfr0[e]     = (short)f2b(sacc[0][e]);
      pfr0[4 + e] = (short)f2b(sacc[1][e]);
      pfr1[e]     = (short)f2b(sacc[2][e]);
      pfr1[4 + e] = (short)f2b(sacc[3][e]);
    }
    __builtin_amdgcn_s_setprio(1);
    #pragma unroll
    for (int dt = 0; dt < 4; dt++){
      bf16x8 vfr0 = *(bf16x8*)&Vts[(dt * 16 + li) * 72 + g * 8];
      bf16x8 vfr1 = *(bf16x8*)&Vts[(dt * 16 + li) * 72 + 32 + g * 8];
      oacc[dt] = __builtin_amdgcn_mfma_f32_16x16x32_bf16(vfr0, pfr0, oacc[dt], 0, 0, 0);
      oacc[dt] = __builtin_amdgcn_mfma_f32_16x16x32_bf16(vfr1, pfr1, oacc[dt], 0, 0, 0);
    }
    __builtin_amdgcn_s_setprio(0);
  }

  float inv = 1.0f / lrun;
  int b = bh >> 3, h = bh & 7;
  u16* op = attnB + (((size_t)(b * 1024 + q0 + w * 16 + li)) << 9) + h * 64 + g * 4;
  #pragma unroll
  for (int dt = 0; dt < 4; dt++){
    us4 pk;
    #pragma unroll
    for (int j = 0; j < 4; j++) pk[j] = f2b(oacc[dt][j] * inv);
    *(us4*)(op + dt * 16) = pk;
  }
}

// ------------------------------------------------------------------
// 10) LN over C + transpose to (B,C,N)
// ------------------------------------------------------------------
__global__ __launch_bounds__(256) void k_ln(const u16* __restrict__ xfB, const float* __restrict__ attnO,
    const float* __restrict__ gamma, const float* __restrict__ beta, float* __restrict__ out){
  __shared__ float mu_s[64], rs_s[64];
  __shared__ float tile[64][65];
  int b = blockIdx.x >> 4, n0 = (blockIdx.x & 15) << 6;
  int t = threadIdx.x, w = t >> 6, lane = t & 63;

  for (int r = w * 16; r < w * 16 + 16; r++){
    size_t rb = ((size_t)(b * 1024 + n0 + r)) << 9;
    const float* ap = attnO + rb + lane * 8;
    const u16*  xp = xfB + rb + lane * 8;
    float4 a0 = *(const float4*)ap;
    float4 a1 = *(const float4*)(ap + 4);
    union { uint4 v; u16 u[8]; } xv; xv.v = *(const uint4*)xp;
    float v0 = a0.x + b2f(xv.u[0]), v1 = a0.y + b2f(xv.u[1]);
    float v2 = a0.z + b2f(xv.u[2]), v3 = a0.w + b2f(xv.u[3]);
    float v4 = a1.x + b2f(xv.u[4]), v5 = a1.y + b2f(xv.u[5]);
    float v6 = a1.z + b2f(xv.u[6]), v7 = a1.w + b2f(xv.u[7]);
    float s  = v0 + v1 + v2 + v3 + v4 + v5 + v6 + v7;
    float s2 = v0*v0 + v1*v1 + v2*v2 + v3*v3 + v4*v4 + v5*v5 + v6*v6 + v7*v7;
    #pragma unroll
    for (int o = 32; o > 0; o >>= 1){ s += __shfl_xor(s, o, 64); s2 += __shfl_xor(s2, o, 64); }
    if (lane == 0){
      float mu = s * (1.0f / 512.0f);
      float var = s2 * (1.0f / 512.0f) - mu * mu;
      mu_s[r] = mu;
      rs_s[r] = 1.0f / sqrtf(var + 1e-5f);
    }
  }
  __syncthreads();

  for (int ch = 0; ch < 8; ch++){
    int c0 = ch * 64;
    {
      int r = t >> 2, cp = (t & 3) << 4;
      size_t rb = (((size_t)(b * 1024 + n0 + r)) << 9) + c0 + cp;
      float mu = mu_s[r], rstd = rs_s[r];
      #pragma unroll
      for (int i2 = 0; i2 < 2; i2++){
        float4 a0 = *(const float4*)(attnO + rb + i2 * 8);
        float4 a1 = *(const float4*)(attnO + rb + i2 * 8 + 4);
        union { uint4 v; u16 u[8]; } xv; xv.v = *(const uint4*)(xfB + rb + i2 * 8);
        float vv[8] = { a0.x + b2f(xv.u[0]), a0.y + b2f(xv.u[1]), a0.z + b2f(xv.u[2]), a0.w + b2f(xv.u[3]),
                        a1.x + b2f(xv.u[4]), a1.y + b2f(xv.u[5]), a1.z + b2f(xv.u[6]), a1.w + b2f(xv.u[7]) };
        #pragma unroll
        for (int i = 0; i < 8; i++){
          int c = c0 + cp + i2 * 8 + i;
          tile[r][cp + i2 * 8 + i] = (vv[i] - mu) * rstd * gamma[c] + beta[c];
        }
      }
    }
    __syncthreads();
    {
      int cl = t >> 2, np_ = (t & 3) << 4;
      float* op = out + (((size_t)(b * 512 + c0 + cl)) << 10) + n0 + np_;
      #pragma unroll
      for (int i = 0; i < 16; i += 4){
        float4 vo = { tile[np_ + i][cl], tile[np_ + i + 1][cl], tile[np_ + i + 2][cl], tile[np_ + i + 3][cl] };
        *(float4*)(op + i) = vo;
      }
    }
    __syncthreads();
  }
}

// ------------------------------------------------------------------
extern "C" void kernel_launch(void* const* d_in, const int* in_sizes, int n_in,
                              void* d_out, int out_size, void* d_ws, size_t ws_size,
                              hipStream_t stream){
  (void)in_sizes; (void)n_in; (void)out_size; (void)ws_size;
  const float* x    = (const float*)d_in[0];
  const float* Wq   = (const float*)d_in[1];
  const float* bq   = (const float*)d_in[2];
  const float* Wk   = (const float*)d_in[3];
  const float* bk   = (const float*)d_in[4];
  const float* Wv   = (const float*)d_in[5];
  const float* bv   = (const float*)d_in[6];
  const float* Wo   = (const float*)d_in[7];
  const float* bo   = (const float*)d_in[8];
  const float* Wsp  = (const float*)d_in[9];
  const float* bsp  = (const float*)d_in[10];
  const float* Wse1 = (const float*)d_in[11];
  const float* bse1 = (const float*)d_in[12];
  const float* Wse2 = (const float*)d_in[13];
  const float* bse2 = (const float*)d_in[14];
  const float* gamma= (const float*)d_in[15];
  const float* beta = (const float*)d_in[16];
  float* out = (float*)d_out;

  char* ws = (char*)d_ws;
  size_t off = 0;
  auto alloc = [&](size_t bytes) -> void* {
    void* p = ws + off;
    off += (bytes + 255) & ~(size_t)255;
    return p;
  };
  u16*   WB     = (u16*)  alloc(1536 * 512 * 2);
  u16*   WoB    = (u16*)  alloc(512 * 512 * 2);
  float* pooled = (float*)alloc(4096 * 4);
  float* cw     = (float*)alloc(4096 * 4);
  float* mbuf   = (float*)alloc(65536 * 4);
  float* bneg   = (float*)alloc(65536 * 4);
  u16*   xfB    = (u16*)  alloc((size_t)8192 * 512 * 2);
  u16*   Qb     = (u16*)  alloc(8388608);
  u16*   Kb     = (u16*)  alloc(8388608);
  u16*   VtG    = (u16*)  alloc(8388608);
  u16*   attnB  = (u16*)  alloc(8388608);
  float* attnO  = (float*)Qb;   // alias Q+K after flash

  k_cvt   <<<dim3(1024), dim3(256), 0, stream>>>(Wq, Wk, Wv, Wo, WB, WoB);
  k_pooled<<<dim3(1024), dim3(256), 0, stream>>>(x, pooled);
  k_se    <<<dim3(8),    dim3(256), 0, stream>>>(pooled, Wse1, bse1, Wse2, bse2, cw);
  k_spxf  <<<dim3(256),  dim3(256), 0, stream>>>(x, Wsp, bsp, cw, mbuf, xfB);
  k_mask  <<<dim3(64),   dim3(64),  0, stream>>>(mbuf, bneg);
  k_gemm_qkv<<<dim3(64, 12), dim3(256), 0, stream>>>(xfB, WB, bq, bk, bv, Qb, Kb, VtG);
  k_flash <<<dim3(1024), dim3(256), 0, stream>>>(Qb, Kb, VtG, bneg, attnB);
  k_gemm_o<<<dim3(64, 4), dim3(256), 0, stream>>>(attnB, WoB, bo, attnO);
  k_ln    <<<dim3(128),  dim3(256), 0, stream>>>(xfB, attnO, gamma, beta, out);
}

// Round 9
// 147.253 us; speedup vs baseline: 1.4257x; 1.0021x over previous
//
#include <hip/hip_runtime.h>
#include <hip/hip_bf16.h>
#include <math.h>

typedef unsigned short u16;
typedef unsigned int u32;
typedef __attribute__((ext_vector_type(4))) float f32x4;
typedef __attribute__((ext_vector_type(8))) short bf16x8;
typedef __attribute__((ext_vector_type(4))) unsigned short us4;
typedef __attribute__((ext_vector_type(8))) unsigned short us8;

#define DI __device__ __forceinline__

// natural -1e9 scaled by log2(e): softmax computed in base-2 domain
#define NEGS  (-1.4426950408889634e9f)
#define QKSCL (0.18033688011112042f)     // 0.125 * log2(e)
#define DEFTH (11.541560327111708f)      // 8 * log2(e)

DI u16 f2b(float x){ __hip_bfloat16 h = __float2bfloat16(x); return *reinterpret_cast<u16*>(&h); }
DI float b2f(u16 u){ union { float f; u32 i; } v; v.i = ((u32)u) << 16; return v.f; }

// packed f32x2 -> bf16x2, single instruction (T12 primitive)
DI u32 cvtpk(float lo, float hi){
  u32 r;
  asm("v_cvt_pk_bf16_f32 %0, %1, %2" : "=v"(r) : "v"(lo), "v"(hi));
  return r;
}
// 2^x direct (v_exp_f32)
DI float exp2a(float x){
  float r;
  asm("v_exp_f32 %0, %1" : "=v"(r) : "v"(x));
  return r;
}

// direct global->LDS DMA, 16B per lane; LDS dest = wave-uniform base + lane*16
DI void gload16(const void* g, void* l){
  __builtin_amdgcn_global_load_lds((const __attribute__((address_space(1))) void*)g,
                                   (__attribute__((address_space(3))) void*)l, 16, 0, 0);
}

// ------------------------------------------------------------------
// 1) weights -> bf16. WB = [Wq;Wk;Wv] (1536x512), WoB = Wo (512x512)
// ------------------------------------------------------------------
__global__ void k_cvt(const float* __restrict__ Wq, const float* __restrict__ Wk,
                      const float* __restrict__ Wv, const float* __restrict__ Wo,
                      u16* __restrict__ WB, u16* __restrict__ WoB){
  int i = blockIdx.x * 256 + threadIdx.x;
  WB[i]          = f2b(Wq[i]);
  WB[262144 + i] = f2b(Wk[i]);
  WB[524288 + i] = f2b(Wv[i]);
  WoB[i]         = f2b(Wo[i]);
}

// ------------------------------------------------------------------
// 2) pooled[b][c] = mean_n x[b][c][n]
// ------------------------------------------------------------------
__global__ __launch_bounds__(256) void k_pooled(const float* __restrict__ x, float* __restrict__ pooled){
  int row  = blockIdx.x * 4 + (threadIdx.x >> 6);
  int lane = threadIdx.x & 63;
  const float4* p = (const float4*)(x + ((size_t)row << 10));
  float4 v0 = p[lane], v1 = p[lane + 64], v2 = p[lane + 128], v3 = p[lane + 192];
  float s = (v0.x + v0.y + v0.z + v0.w) + (v1.x + v1.y + v1.z + v1.w)
          + (v2.x + v2.y + v2.z + v2.w) + (v3.x + v3.y + v3.z + v3.w);
  #pragma unroll
  for (int o = 32; o > 0; o >>= 1) s += __shfl_down(s, o, 64);
  if (lane == 0) pooled[row] = s * (1.0f / 1024.0f);
}

// ------------------------------------------------------------------
// 3) SE
// ------------------------------------------------------------------
__global__ __launch_bounds__(256) void k_se(const float* __restrict__ pooled,
    const float* __restrict__ Wse1, const float* __restrict__ bse1,
    const float* __restrict__ Wse2, const float* __restrict__ bse2,
    float* __restrict__ cw){
  __shared__ float pl[512];
  __shared__ float h1[32];
  int b = blockIdx.x, t = threadIdx.x;
  pl[t] = pooled[b * 512 + t];
  pl[t + 256] = pooled[b * 512 + t + 256];
  __syncthreads();
  if (t < 32){
    float acc = bse1[t];
    const float* w = Wse1 + t * 512;
    for (int c = 0; c < 512; c++) acc = fmaf(pl[c], w[c], acc);
    h1[t] = fmaxf(acc, 0.0f);
  }
  __syncthreads();
  for (int c = t; c < 512; c += 256){
    float acc = bse2[c];
    const float* w = Wse2 + c * 32;
    #pragma unroll
    for (int j = 0; j < 32; j++) acc = fmaf(h1[j], w[j], acc);
    cw[b * 512 + c] = 1.0f / (1.0f + expf(-acc));
  }
}

// ------------------------------------------------------------------
// 4+6 fused) k_spxf: one pass over x producing mbuf (f32) + xfB (bf16^T)
// ------------------------------------------------------------------
__global__ __launch_bounds__(256) void k_spxf(const float* __restrict__ x,
    const float* __restrict__ Wsp, const float* __restrict__ bsp,
    const float* __restrict__ cw, float* __restrict__ mbuf, u16* __restrict__ xfB){
  __shared__ float wsh[4096];
  __shared__ float cwl[512];
  __shared__ float tile[64][36];
  __shared__ float part[8][256];
  int t = threadIdx.x;
  int b = blockIdx.x >> 5, n0 = (blockIdx.x & 31) << 5;
  for (int i = t; i < 4096; i += 256) wsh[i] = Wsp[i];
  cwl[t] = cw[b * 512 + t];
  cwl[t + 256] = cw[b * 512 + t + 256];

  int nl = t & 31, cg = t >> 5;
  int lr = t >> 2, lc = (t & 3) << 3;
  float acc[8] = {0,0,0,0,0,0,0,0};

  for (int cb = 0; cb < 8; cb++){
    __syncthreads();
    const float* xp = x + ((size_t)(b * 512 + cb * 64 + lr) << 10) + n0 + lc;
    float4 v0 = *(const float4*)xp;
    float4 v1 = *(const float4*)(xp + 4);
    *(float4*)&tile[lr][lc]     = v0;
    *(float4*)&tile[lr][lc + 4] = v1;
    __syncthreads();
    float sc[8];
    #pragma unroll
    for (int i = 0; i < 8; i++){
      int c = cb * 64 + cg * 8 + i;
      float v = tile[cg * 8 + i][nl];
      sc[i] = v * cwl[c];
      #pragma unroll
      for (int h = 0; h < 8; h++) acc[h] = fmaf(v, wsh[(h << 9) + c], acc[h]);
    }
    union { u32 d[4]; us8 v; } xu;
    #pragma unroll
    for (int i = 0; i < 4; i++) xu.d[i] = cvtpk(sc[2*i], sc[2*i+1]);
    *(us8*)&xfB[(((size_t)(b * 1024 + n0 + nl)) << 9) + cb * 64 + cg * 8] = xu.v;
  }
  #pragma unroll
  for (int h = 0; h < 8; h++) part[cg][h * 32 + nl] = acc[h];
  __syncthreads();
  {
    int h = t >> 5, px = t & 31;
    float s = bsp[h];
    #pragma unroll
    for (int g2 = 0; g2 < 8; g2++) s += part[g2][h * 32 + px];
    mbuf[(((size_t)(b * 8 + h)) << 10) + n0 + px] = 1.0f / (1.0f + expf(-s));
  }
}

// ------------------------------------------------------------------
// 5) adaptive pool 7x7, threshold, upsample -> bneg (B,8,N) in {0, NEGS}
// ------------------------------------------------------------------
__global__ void k_mask(const float* __restrict__ mbuf, float* __restrict__ bneg){
  __shared__ float sm[1024];
  __shared__ float mg[49];
  int bh = blockIdx.x, t = threadIdx.x;
  const float* mp = mbuf + ((size_t)bh << 10);
  for (int i = t; i < 1024; i += 64) sm[i] = mp[i];
  __syncthreads();
  if (t < 49){
    int ci = t / 7, cj = t % 7;
    int r0 = (ci * 32) / 7, r1 = ((ci + 1) * 32 + 6) / 7;
    int c0 = (cj * 32) / 7, c1 = ((cj + 1) * 32 + 6) / 7;
    float acc = 0.0f;
    for (int cc = c0; cc < c1; cc++){
      float rs = 0.0f;
      for (int rr = r0; rr < r1; rr++) rs += sm[rr * 32 + cc];
      acc += rs / (float)(r1 - r0);
    }
    float v = acc / (float)(c1 - c0);
    mg[t] = (v > 0.5f) ? 1.0f : 0.0f;
  }
  __syncthreads();
  for (int i = t; i < 1024; i += 64){
    int r = i >> 5, c = i & 31;
    float m = mg[((r * 7) >> 5) * 7 + ((c * 7) >> 5)];
    bneg[((size_t)bh << 10) + i] = (m > 0.5f) ? 0.0f : NEGS;
  }
}

// ------------------------------------------------------------------
// 7/9) bf16 MFMA GEMM — dbuf global_load_lds(16B), BK=32, one barrier/step.
//   Pre-swizzled global source -> conflict-free ds_read_b128.
//   Coalesced LDS-staged epilogue (cvt_pk packing).
// ------------------------------------------------------------------
template<int MODE>
DI void gemm_body(const u16* __restrict__ A, const u16* __restrict__ Bw,
    const float* __restrict__ b0, const float* __restrict__ b1, const float* __restrict__ b2,
    u16* __restrict__ outQ, u16* __restrict__ outK, u16* __restrict__ outV, float* __restrict__ outF){
  __shared__ __align__(16) u16 smem[16384];
  int m0 = blockIdx.x * 128, n0 = blockIdx.y * 128;
  bool vblk = (MODE == 0) && (n0 >= 1024);
  int t = threadIdx.x, lane = t & 63, w = t >> 6;
  int wr = w >> 1, wc = w & 1;
  int g = lane >> 4, li = lane & 15;
  f32x4 acc[4][4];
  #pragma unroll
  for (int mt = 0; mt < 4; mt++)
    #pragma unroll
    for (int nt = 0; nt < 4; nt++) acc[mt][nt] = (f32x4){0.f, 0.f, 0.f, 0.f};

  int cof = (((lane & 3) ^ ((lane >> 3) & 3)) << 3);
  int rl = lane >> 2;
  const u16* gA = A  + (size_t)(m0 + w * 32 + rl) * 512 + cof;
  const u16* gB = Bw + (size_t)(n0 + w * 32 + rl) * 512 + cof;
  u16* lA = smem + (w * 32) * 32;
  u16* lB = smem + 4096 + (w * 32) * 32;

  #define STAGE(buf, k0)                                              \
    gload16(gA + (k0),            lA + (buf) * 8192);                 \
    gload16(gA + (k0) + 16 * 512, lA + (buf) * 8192 + 512);           \
    gload16(gB + (k0),            lB + (buf) * 8192);                 \
    gload16(gB + (k0) + 16 * 512, lB + (buf) * 8192 + 512);

  STAGE(0, 0);
  __syncthreads();

  int rsw = ((li >> 1) & 3);
  int cA = (g ^ rsw) << 3;
  int cur = 0;
  for (int ks = 0; ks < 16; ks++){
    if (ks < 15){ STAGE(cur ^ 1, (ks + 1) * 32); }
    const u16* Ac = smem + cur * 8192;
    const u16* Bc = smem + cur * 8192 + 4096;
    bf16x8 afr[4], bfr[4];
    #pragma unroll
    for (int mt = 0; mt < 4; mt++)
      afr[mt] = *(const bf16x8*)&Ac[(wr * 64 + mt * 16 + li) * 32 + cA];
    #pragma unroll
    for (int nt = 0; nt < 4; nt++)
      bfr[nt] = *(const bf16x8*)&Bc[(wc * 64 + nt * 16 + li) * 32 + cA];
    if (vblk){
      #pragma unroll
      for (int mt = 0; mt < 4; mt++)
        #pragma unroll
        for (int nt = 0; nt < 4; nt++)
          acc[mt][nt] = __builtin_amdgcn_mfma_f32_16x16x32_bf16(afr[mt], bfr[nt], acc[mt][nt], 0, 0, 0);
    } else {
      #pragma unroll
      for (int mt = 0; mt < 4; mt++)
        #pragma unroll
        for (int nt = 0; nt < 4; nt++)
          acc[mt][nt] = __builtin_amdgcn_mfma_f32_16x16x32_bf16(bfr[nt], afr[mt], acc[mt][nt], 0, 0, 0);
    }
    __syncthreads();
    cur ^= 1;
  }
  #undef STAGE

  if (MODE == 1){
    #pragma unroll
    for (int mt = 0; mt < 4; mt++){
      #pragma unroll
      for (int nt = 0; nt < 4; nt++){
        int m = m0 + wr * 64 + mt * 16 + li;
        int obase = n0 + wc * 64 + nt * 16 + (g << 2);
        float4 bias4 = *(const float4*)&b0[obase];
        float4 vo = { acc[mt][nt][0] + bias4.x, acc[mt][nt][1] + bias4.y,
                      acc[mt][nt][2] + bias4.z, acc[mt][nt][3] + bias4.w };
        *(float4*)&outF[(size_t)m * 512 + obase] = vo;
      }
    }
    return;
  }

  // ---- MODE 0: two-pass LDS-staged coalesced epilogue
  u16* Cl = smem;   // 64 x 136
  const float* bb = vblk ? b2 : ((n0 >> 9) ? b1 : b0);
  #pragma unroll
  for (int p = 0; p < 2; p++){
    __syncthreads();
    if (vblk){
      if (wc == p){
        #pragma unroll
        for (int mt = 0; mt < 4; mt++){
          #pragma unroll
          for (int nt = 0; nt < 4; nt++){
            int row = nt * 16 + li;
            float bias = bb[(n0 & 511) + p * 64 + row];
            int col = wr * 64 + ((mt >> 1) << 5) + (g << 3) + ((mt & 1) << 2);
            union { u32 d[2]; us4 v; } pu;
            pu.d[0] = cvtpk(acc[mt][nt][0] + bias, acc[mt][nt][1] + bias);
            pu.d[1] = cvtpk(acc[mt][nt][2] + bias, acc[mt][nt][3] + bias);
            *(us4*)&Cl[row * 136 + col] = pu.v;
          }
        }
      }
    } else {
      if (wr == p){
        #pragma unroll
        for (int mt = 0; mt < 4; mt++){
          #pragma unroll
          for (int nt = 0; nt < 4; nt++){
            int row = mt * 16 + li;
            int ob = wc * 64 + nt * 16 + (g << 2);
            float4 bias4 = *(const float4*)&bb[(n0 & 511) + ob];
            union { u32 d[2]; us4 v; } pu;
            pu.d[0] = cvtpk(acc[mt][nt][0] + bias4.x, acc[mt][nt][1] + bias4.y);
            pu.d[1] = cvtpk(acc[mt][nt][2] + bias4.z, acc[mt][nt][3] + bias4.w);
            *(us4*)&Cl[row * 136 + ob] = pu.v;
          }
        }
      }
    }
    __syncthreads();
    int r = t >> 4, ol = (t & 15) << 3;
    if (vblk){
      int b = m0 >> 10, nt0 = m0 & 1023;
      #pragma unroll
      for (int pp = 0; pp < 4; pp++){
        int rr = pp * 16 + r;
        int c = (n0 & 511) + p * 64 + rr, h = c >> 6, dv = c & 63;
        us8 v = *(us8*)&Cl[rr * 136 + ol];
        *(us8*)&outV[(((size_t)(b * 8 + h)) << 16) + ((size_t)dv << 10) + nt0 + ol] = v;
      }
    } else {
      u16* base = (n0 >> 9) ? outK : outQ;
      #pragma unroll
      for (int pp = 0; pp < 4; pp++){
        int rr = pp * 16 + r;
        int m = m0 + p * 64 + rr, b = m >> 10, n = m & 1023;
        int c = (n0 & 511) + ol, h = c >> 6, dv = c & 63;
        us8 v = *(us8*)&Cl[rr * 136 + ol];
        *(us8*)&base[(((size_t)(b * 8 + h)) << 16) + ((size_t)n << 6) + dv] = v;
      }
    }
  }
}

__global__ __launch_bounds__(256) void k_gemm_qkv(const u16* __restrict__ A, const u16* __restrict__ Bw,
    const float* __restrict__ b0, const float* __restrict__ b1, const float* __restrict__ b2,
    u16* __restrict__ outQ, u16* __restrict__ outK, u16* __restrict__ outV){
  gemm_body<0>(A, Bw, b0, b1, b2, outQ, outK, outV, nullptr);
}

__global__ __launch_bounds__(256) void k_gemm_o(const u16* __restrict__ A, const u16* __restrict__ Bw,
    const float* __restrict__ b0, float* __restrict__ outF){
  gemm_body<1>(A, Bw, b0, nullptr, nullptr, nullptr, nullptr, nullptr, outF);
}

// ------------------------------------------------------------------
// 8) flash attention, swapped-operand, base-2 softmax domain,
//    cvt_pk packing, tree reductions, XCD swizzle, defer-max, setprio.
// ------------------------------------------------------------------
__global__ __launch_bounds__(256) void k_flash(const u16* __restrict__ Q, const u16* __restrict__ K,
    const u16* __restrict__ Vt, const float* __restrict__ bneg, u16* __restrict__ attnB){
  __shared__ __align__(16) u16 Ks[64 * 72];
  __shared__ __align__(16) u16 Vts[64 * 72];
  __shared__ float mks[64];
  int hw = blockIdx.x;
  int bid = ((hw & 7) << 7) + (hw >> 3);
  int bh = bid >> 4, q0 = (bid & 15) << 6;
  int t = threadIdx.x, lane = t & 63, w = t >> 6;
  int g = lane >> 4, li = lane & 15;

  const u16* Kp = K  + ((size_t)bh << 16);
  const u16* Vp = Vt + ((size_t)bh << 16);
  const float* bp = bneg + ((size_t)bh << 10);

  bf16x8 qfr0, qfr1;
  {
    const u16* qrow = Q + ((size_t)bh << 16) + ((size_t)(q0 + w * 16 + li) << 6);
    qfr0 = *(const bf16x8*)(qrow + g * 8);
    qfr1 = *(const bf16x8*)(qrow + 32 + g * 8);
  }
  float bnq = bp[q0 + w * 16 + li];

  f32x4 oacc[4];
  #pragma unroll
  for (int dt = 0; dt < 4; dt++) oacc[dt] = (f32x4){0.f, 0.f, 0.f, 0.f};
  float mrun = -INFINITY, lrun = 0.0f;

  int sr = t >> 2, sc = (t & 3) << 4;
  const u16* kg = Kp + ((size_t)sr << 6) + sc;
  const u16* vg = Vp + ((size_t)sr << 10) + sc;
  uint4 kr0, kr1, vr0, vr1;
  float mr = 0.0f;
  kr0 = *(const uint4*)(kg);
  kr1 = *(const uint4*)(kg + 8);
  vr0 = *(const uint4*)(vg);
  vr1 = *(const uint4*)(vg + 8);
  if (t < 64) mr = bp[t];

  for (int kt = 0; kt < 16; kt++){
    __syncthreads();
    *(uint4*)&Ks[sr * 72 + sc]      = kr0;
    *(uint4*)&Ks[sr * 72 + sc + 8]  = kr1;
    *(uint4*)&Vts[sr * 72 + sc]     = vr0;
    *(uint4*)&Vts[sr * 72 + sc + 8] = vr1;
    if (t < 64) mks[t] = mr;
    if (kt < 15){
      kr0 = *(const uint4*)(kg + (kt + 1) * 4096);
      kr1 = *(const uint4*)(kg + (kt + 1) * 4096 + 8);
      vr0 = *(const uint4*)(vg + (kt + 1) * 64);
      vr1 = *(const uint4*)(vg + (kt + 1) * 64 + 8);
      if (t < 64) mr = bp[(kt + 1) * 64 + t];
    }
    __syncthreads();

    f32x4 sacc[4];
    #pragma unroll
    for (int mt = 0; mt < 4; mt++) sacc[mt] = (f32x4){0.f, 0.f, 0.f, 0.f};
    __builtin_amdgcn_s_setprio(1);
    #pragma unroll
    for (int mt = 0; mt < 4; mt++){
      bf16x8 kfr0 = *(bf16x8*)&Ks[(mt * 16 + li) * 72 + g * 8];
      bf16x8 kfr1 = *(bf16x8*)&Ks[(mt * 16 + li) * 72 + 32 + g * 8];
      sacc[mt] = __builtin_amdgcn_mfma_f32_16x16x32_bf16(kfr0, qfr0, sacc[mt], 0, 0, 0);
      sacc[mt] = __builtin_amdgcn_mfma_f32_16x16x32_bf16(kfr1, qfr1, sacc[mt], 0, 0, 0);
    }
    __builtin_amdgcn_s_setprio(0);

    // bias + scale into base-2 domain; tree max (4 parallel chains)
    float tm[4];
    #pragma unroll
    for (int mt = 0; mt < 4; mt++){
      float4 bk = *(const float4*)&mks[mt * 16 + g * 4];
      float s0 = fmaf(sacc[mt][0], QKSCL, fminf(bk.x, bnq));
      float s1 = fmaf(sacc[mt][1], QKSCL, fminf(bk.y, bnq));
      float s2 = fmaf(sacc[mt][2], QKSCL, fminf(bk.z, bnq));
      float s3 = fmaf(sacc[mt][3], QKSCL, fminf(bk.w, bnq));
      sacc[mt][0] = s0; sacc[mt][1] = s1; sacc[mt][2] = s2; sacc[mt][3] = s3;
      tm[mt] = fmaxf(fmaxf(s0, s1), fmaxf(s2, s3));
    }
    float tmax = fmaxf(fmaxf(tm[0], tm[1]), fmaxf(tm[2], tm[3]));
    tmax = fmaxf(tmax, __shfl_xor(tmax, 16, 64));
    tmax = fmaxf(tmax, __shfl_xor(tmax, 32, 64));

    // defer-max (T13), base-2 threshold
    if (!__all(tmax <= mrun + DEFTH)){
      float mnew = fmaxf(mrun, tmax);
      float scl = exp2a(mrun - mnew);
      mrun = mnew;
      lrun *= scl;
      #pragma unroll
      for (int dt = 0; dt < 4; dt++)
        #pragma unroll
        for (int j = 0; j < 4; j++) oacc[dt][j] *= scl;
    }

    // exp2 + tree sum (4 parallel chains)
    float rs[4];
    #pragma unroll
    for (int mt = 0; mt < 4; mt++){
      float p0 = exp2a(sacc[mt][0] - mrun);
      float p1 = exp2a(sacc[mt][1] - mrun);
      float p2 = exp2a(sacc[mt][2] - mrun);
      float p3 = exp2a(sacc[mt][3] - mrun);
      sacc[mt][0] = p0; sacc[mt][1] = p1; sacc[mt][2] = p2; sacc[mt][3] = p3;
      rs[mt] = (p0 + p1) + (p2 + p3);
    }
    float rsum = (rs[0] + rs[1]) + (rs[2] + rs[3]);
    rsum += __shfl_xor(rsum, 16, 64);
    rsum += __shfl_xor(rsum, 32, 64);
    lrun += rsum;

    // pack P via cvt_pk (slot s=g*8+e <-> key 16*(e>=4)+4g+(e&3))
    union { u32 d[4]; bf16x8 v; } u0, u1;
    u0.d[0] = cvtpk(sacc[0][0], sacc[0][1]);
    u0.d[1] = cvtpk(sacc[0][2], sacc[0][3]);
    u0.d[2] = cvtpk(sacc[1][0], sacc[1][1]);
    u0.d[3] = cvtpk(sacc[1][2], sacc[1][3]);
    u1.d[0] = cvtpk(sacc[2][0], sacc[2][1]);
    u1.d[1] = cvtpk(sacc[2][2], sacc[2][3]);
    u1.d[2] = cvtpk(sacc[3][0], sacc[3][1]);
    u1.d[3] = cvtpk(sacc[3][2], sacc[3][3]);

    __builtin_amdgcn_s_setprio(1);
    #pragma unroll
    for (int dt = 0; dt < 4; dt++){
      bf16x8 vfr0 = *(bf16x8*)&Vts[(dt * 16 + li) * 72 + g * 8];
      bf16x8 vfr1 = *(bf16x8*)&Vts[(dt * 16 + li) * 72 + 32 + g * 8];
      oacc[dt] = __builtin_amdgcn_mfma_f32_16x16x32_bf16(vfr0, u0.v, oacc[dt], 0, 0, 0);
      oacc[dt] = __builtin_amdgcn_mfma_f32_16x16x32_bf16(vfr1, u1.v, oacc[dt], 0, 0, 0);
    }
    __builtin_amdgcn_s_setprio(0);
  }

  float inv = 1.0f / lrun;
  int b = bh >> 3, h = bh & 7;
  u16* op = attnB + (((size_t)(b * 1024 + q0 + w * 16 + li)) << 9) + h * 64 + g * 4;
  #pragma unroll
  for (int dt = 0; dt < 4; dt++){
    union { u32 d[2]; us4 v; } ou;
    ou.d[0] = cvtpk(oacc[dt][0] * inv, oacc[dt][1] * inv);
    ou.d[1] = cvtpk(oacc[dt][2] * inv, oacc[dt][3] * inv);
    *(us4*)(op + dt * 16) = ou.v;
  }
}

// ------------------------------------------------------------------
// 10) LN over C + transpose to (B,C,N)
// ------------------------------------------------------------------
__global__ __launch_bounds__(256) void k_ln(const u16* __restrict__ xfB, const float* __restrict__ attnO,
    const float* __restrict__ gamma, const float* __restrict__ beta, float* __restrict__ out){
  __shared__ float mu_s[64], rs_s[64];
  __shared__ float tile[64][65];
  int b = blockIdx.x >> 4, n0 = (blockIdx.x & 15) << 6;
  int t = threadIdx.x, w = t >> 6, lane = t & 63;

  for (int r = w * 16; r < w * 16 + 16; r++){
    size_t rb = ((size_t)(b * 1024 + n0 + r)) << 9;
    const float* ap = attnO + rb + lane * 8;
    const u16*  xp = xfB + rb + lane * 8;
    float4 a0 = *(const float4*)ap;
    float4 a1 = *(const float4*)(ap + 4);
    union { uint4 v; u16 u[8]; } xv; xv.v = *(const uint4*)xp;
    float v0 = a0.x + b2f(xv.u[0]), v1 = a0.y + b2f(xv.u[1]);
    float v2 = a0.z + b2f(xv.u[2]), v3 = a0.w + b2f(xv.u[3]);
    float v4 = a1.x + b2f(xv.u[4]), v5 = a1.y + b2f(xv.u[5]);
    float v6 = a1.z + b2f(xv.u[6]), v7 = a1.w + b2f(xv.u[7]);
    float s  = v0 + v1 + v2 + v3 + v4 + v5 + v6 + v7;
    float s2 = v0*v0 + v1*v1 + v2*v2 + v3*v3 + v4*v4 + v5*v5 + v6*v6 + v7*v7;
    #pragma unroll
    for (int o = 32; o > 0; o >>= 1){ s += __shfl_xor(s, o, 64); s2 += __shfl_xor(s2, o, 64); }
    if (lane == 0){
      float mu = s * (1.0f / 512.0f);
      float var = s2 * (1.0f / 512.0f) - mu * mu;
      mu_s[r] = mu;
      rs_s[r] = 1.0f / sqrtf(var + 1e-5f);
    }
  }
  __syncthreads();

  for (int ch = 0; ch < 8; ch++){
    int c0 = ch * 64;
    {
      int r = t >> 2, cp = (t & 3) << 4;
      size_t rb = (((size_t)(b * 1024 + n0 + r)) << 9) + c0 + cp;
      float mu = mu_s[r], rstd = rs_s[r];
      #pragma unroll
      for (int i2 = 0; i2 < 2; i2++){
        float4 a0 = *(const float4*)(attnO + rb + i2 * 8);
        float4 a1 = *(const float4*)(attnO + rb + i2 * 8 + 4);
        union { uint4 v; u16 u[8]; } xv; xv.v = *(const uint4*)(xfB + rb + i2 * 8);
        float vv[8] = { a0.x + b2f(xv.u[0]), a0.y + b2f(xv.u[1]), a0.z + b2f(xv.u[2]), a0.w + b2f(xv.u[3]),
                        a1.x + b2f(xv.u[4]), a1.y + b2f(xv.u[5]), a1.z + b2f(xv.u[6]), a1.w + b2f(xv.u[7]) };
        #pragma unroll
        for (int i = 0; i < 8; i++){
          int c = c0 + cp + i2 * 8 + i;
          tile[r][cp + i2 * 8 + i] = (vv[i] - mu) * rstd * gamma[c] + beta[c];
        }
      }
    }
    __syncthreads();
    {
      int cl = t >> 2, np_ = (t & 3) << 4;
      float* op = out + (((size_t)(b * 512 + c0 + cl)) << 10) + n0 + np_;
      #pragma unroll
      for (int i = 0; i < 16; i += 4){
        float4 vo = { tile[np_ + i][cl], tile[np_ + i + 1][cl], tile[np_ + i + 2][cl], tile[np_ + i + 3][cl] };
        *(float4*)(op + i) = vo;
      }
    }
    __syncthreads();
  }
}

// ------------------------------------------------------------------
extern "C" void kernel_launch(void* const* d_in, const int* in_sizes, int n_in,
                              void* d_out, int out_size, void* d_ws, size_t ws_size,
                              hipStream_t stream){
  (void)in_sizes; (void)n_in; (void)out_size; (void)ws_size;
  const float* x    = (const float*)d_in[0];
  const float* Wq   = (const float*)d_in[1];
  const float* bq   = (const float*)d_in[2];
  const float* Wk   = (const float*)d_in[3];
  const float* bk   = (const float*)d_in[4];
  const float* Wv   = (const float*)d_in[5];
  const float* bv   = (const float*)d_in[6];
  const float* Wo   = (const float*)d_in[7];
  const float* bo   = (const float*)d_in[8];
  const float* Wsp  = (const float*)d_in[9];
  const float* bsp  = (const float*)d_in[10];
  const float* Wse1 = (const float*)d_in[11];
  const float* bse1 = (const float*)d_in[12];
  const float* Wse2 = (const float*)d_in[13];
  const float* bse2 = (const float*)d_in[14];
  const float* gamma= (const float*)d_in[15];
  const float* beta = (const float*)d_in[16];
  float* out = (float*)d_out;

  char* ws = (char*)d_ws;
  size_t off = 0;
  auto alloc = [&](size_t bytes) -> void* {
    void* p = ws + off;
    off += (bytes + 255) & ~(size_t)255;
    return p;
  };
  u16*   WB     = (u16*)  alloc(1536 * 512 * 2);
  u16*   WoB    = (u16*)  alloc(512 * 512 * 2);
  float* pooled = (float*)alloc(4096 * 4);
  float* cw     = (float*)alloc(4096 * 4);
  float* mbuf   = (float*)alloc(65536 * 4);
  float* bneg   = (float*)alloc(65536 * 4);
  u16*   xfB    = (u16*)  alloc((size_t)8192 * 512 * 2);
  u16*   Qb     = (u16*)  alloc(8388608);
  u16*   Kb     = (u16*)  alloc(8388608);
  u16*   VtG    = (u16*)  alloc(8388608);
  u16*   attnB  = (u16*)  alloc(8388608);
  float* attnO  = (float*)Qb;   // alias Q+K after flash

  k_cvt   <<<dim3(1024), dim3(256), 0, stream>>>(Wq, Wk, Wv, Wo, WB, WoB);
  k_pooled<<<dim3(1024), dim3(256), 0, stream>>>(x, pooled);
  k_se    <<<dim3(8),    dim3(256), 0, stream>>>(pooled, Wse1, bse1, Wse2, bse2, cw);
  k_spxf  <<<dim3(256),  dim3(256), 0, stream>>>(x, Wsp, bsp, cw, mbuf, xfB);
  k_mask  <<<dim3(64),   dim3(64),  0, stream>>>(mbuf, bneg);
  k_gemm_qkv<<<dim3(64, 12), dim3(256), 0, stream>>>(xfB, WB, bq, bk, bv, Qb, Kb, VtG);
  k_flash <<<dim3(1024), dim3(256), 0, stream>>>(Qb, Kb, VtG, bneg, attnB);
  k_gemm_o<<<dim3(64, 4), dim3(256), 0, stream>>>(attnB, WoB, bo, attnO);
  k_ln    <<<dim3(128),  dim3(256), 0, stream>>>(xfB, attnO, gamma, beta, out);
}

// Round 11
// 141.676 us; speedup vs baseline: 1.4818x; 1.0394x over previous
//
#include <hip/hip_runtime.h>
#include <hip/hip_bf16.h>
#include <math.h>

typedef unsigned short u16;
typedef unsigned int u32;
typedef __attribute__((ext_vector_type(4))) float f32x4;
typedef __attribute__((ext_vector_type(8))) short bf16x8;
typedef __attribute__((ext_vector_type(4))) unsigned short us4;
typedef __attribute__((ext_vector_type(8))) unsigned short us8;

#define DI __device__ __forceinline__

// natural -1e9 scaled by log2(e): softmax computed in base-2 domain
#define NEGS  (-1.4426950408889634e9f)
#define QKSCL (0.18033688011112042f)     // 0.125 * log2(e)
#define DEFTH (11.541560327111708f)      // 8 * log2(e)

DI u16 f2b(float x){ __hip_bfloat16 h = __float2bfloat16(x); return *reinterpret_cast<u16*>(&h); }
DI float b2f(u16 u){ union { float f; u32 i; } v; v.i = ((u32)u) << 16; return v.f; }

DI u32 cvtpk(float lo, float hi){
  u32 r;
  asm("v_cvt_pk_bf16_f32 %0, %1, %2" : "=v"(r) : "v"(lo), "v"(hi));
  return r;
}
DI float exp2a(float x){
  float r;
  asm("v_exp_f32 %0, %1" : "=v"(r) : "v"(x));
  return r;
}

// direct global->LDS DMA, 16B per lane; LDS dest = wave-uniform base + lane*16
DI void gload16(const void* g, void* l){
  __builtin_amdgcn_global_load_lds((const __attribute__((address_space(1))) void*)g,
                                   (__attribute__((address_space(3))) void*)l, 16, 0, 0);
}

// ------------------------------------------------------------------
// 1) weights -> bf16
// ------------------------------------------------------------------
__global__ void k_cvt(const float* __restrict__ Wq, const float* __restrict__ Wk,
                      const float* __restrict__ Wv, const float* __restrict__ Wo,
                      u16* __restrict__ WB, u16* __restrict__ WoB){
  int i = blockIdx.x * 256 + threadIdx.x;
  WB[i]          = f2b(Wq[i]);
  WB[262144 + i] = f2b(Wk[i]);
  WB[524288 + i] = f2b(Wv[i]);
  WoB[i]         = f2b(Wo[i]);
}

// ------------------------------------------------------------------
// 2) pooled[b][c] = mean_n x[b][c][n]
// ------------------------------------------------------------------
__global__ __launch_bounds__(256) void k_pooled(const float* __restrict__ x, float* __restrict__ pooled){
  int row  = blockIdx.x * 4 + (threadIdx.x >> 6);
  int lane = threadIdx.x & 63;
  const float4* p = (const float4*)(x + ((size_t)row << 10));
  float4 v0 = p[lane], v1 = p[lane + 64], v2 = p[lane + 128], v3 = p[lane + 192];
  float s = (v0.x + v0.y + v0.z + v0.w) + (v1.x + v1.y + v1.z + v1.w)
          + (v2.x + v2.y + v2.z + v2.w) + (v3.x + v3.y + v3.z + v3.w);
  #pragma unroll
  for (int o = 32; o > 0; o >>= 1) s += __shfl_down(s, o, 64);
  if (lane == 0) pooled[row] = s * (1.0f / 1024.0f);
}

// ------------------------------------------------------------------
// 3) SE
// ------------------------------------------------------------------
__global__ __launch_bounds__(256) void k_se(const float* __restrict__ pooled,
    const float* __restrict__ Wse1, const float* __restrict__ bse1,
    const float* __restrict__ Wse2, const float* __restrict__ bse2,
    float* __restrict__ cw){
  __shared__ float pl[512];
  __shared__ float h1[32];
  int b = blockIdx.x, t = threadIdx.x;
  pl[t] = pooled[b * 512 + t];
  pl[t + 256] = pooled[b * 512 + t + 256];
  __syncthreads();
  if (t < 32){
    float acc = bse1[t];
    const float* w = Wse1 + t * 512;
    for (int c = 0; c < 512; c++) acc = fmaf(pl[c], w[c], acc);
    h1[t] = fmaxf(acc, 0.0f);
  }
  __syncthreads();
  for (int c = t; c < 512; c += 256){
    float acc = bse2[c];
    const float* w = Wse2 + c * 32;
    #pragma unroll
    for (int j = 0; j < 32; j++) acc = fmaf(h1[j], w[j], acc);
    cw[b * 512 + c] = 1.0f / (1.0f + expf(-acc));
  }
}

// ------------------------------------------------------------------
// 4+6 fused) k_spxf: one pass over x producing mbuf (f32) + xfB (bf16^T)
// ------------------------------------------------------------------
__global__ __launch_bounds__(256) void k_spxf(const float* __restrict__ x,
    const float* __restrict__ Wsp, const float* __restrict__ bsp,
    const float* __restrict__ cw, float* __restrict__ mbuf, u16* __restrict__ xfB){
  __shared__ float wsh[4096];
  __shared__ float cwl[512];
  __shared__ float tile[64][36];
  __shared__ float part[8][256];
  int t = threadIdx.x;
  int b = blockIdx.x >> 5, n0 = (blockIdx.x & 31) << 5;
  for (int i = t; i < 4096; i += 256) wsh[i] = Wsp[i];
  cwl[t] = cw[b * 512 + t];
  cwl[t + 256] = cw[b * 512 + t + 256];

  int nl = t & 31, cg = t >> 5;
  int lr = t >> 2, lc = (t & 3) << 3;
  float acc[8] = {0,0,0,0,0,0,0,0};

  for (int cb = 0; cb < 8; cb++){
    __syncthreads();
    const float* xp = x + ((size_t)(b * 512 + cb * 64 + lr) << 10) + n0 + lc;
    float4 v0 = *(const float4*)xp;
    float4 v1 = *(const float4*)(xp + 4);
    *(float4*)&tile[lr][lc]     = v0;
    *(float4*)&tile[lr][lc + 4] = v1;
    __syncthreads();
    float sc[8];
    #pragma unroll
    for (int i = 0; i < 8; i++){
      int c = cb * 64 + cg * 8 + i;
      float v = tile[cg * 8 + i][nl];
      sc[i] = v * cwl[c];
      #pragma unroll
      for (int h = 0; h < 8; h++) acc[h] = fmaf(v, wsh[(h << 9) + c], acc[h]);
    }
    union { u32 d[4]; us8 v; } xu;
    #pragma unroll
    for (int i = 0; i < 4; i++) xu.d[i] = cvtpk(sc[2*i], sc[2*i+1]);
    *(us8*)&xfB[(((size_t)(b * 1024 + n0 + nl)) << 9) + cb * 64 + cg * 8] = xu.v;
  }
  #pragma unroll
  for (int h = 0; h < 8; h++) part[cg][h * 32 + nl] = acc[h];
  __syncthreads();
  {
    int h = t >> 5, px = t & 31;
    float s = bsp[h];
    #pragma unroll
    for (int g2 = 0; g2 < 8; g2++) s += part[g2][h * 32 + px];
    mbuf[(((size_t)(b * 8 + h)) << 10) + n0 + px] = 1.0f / (1.0f + expf(-s));
  }
}

// ------------------------------------------------------------------
// 5) adaptive pool 7x7, threshold, upsample -> bneg (B,8,N) in {0, NEGS}
// ------------------------------------------------------------------
__global__ void k_mask(const float* __restrict__ mbuf, float* __restrict__ bneg){
  __shared__ float sm[1024];
  __shared__ float mg[49];
  int bh = blockIdx.x, t = threadIdx.x;
  const float* mp = mbuf + ((size_t)bh << 10);
  for (int i = t; i < 1024; i += 64) sm[i] = mp[i];
  __syncthreads();
  if (t < 49){
    int ci = t / 7, cj = t % 7;
    int r0 = (ci * 32) / 7, r1 = ((ci + 1) * 32 + 6) / 7;
    int c0 = (cj * 32) / 7, c1 = ((cj + 1) * 32 + 6) / 7;
    float acc = 0.0f;
    for (int cc = c0; cc < c1; cc++){
      float rs = 0.0f;
      for (int rr = r0; rr < r1; rr++) rs += sm[rr * 32 + cc];
      acc += rs / (float)(r1 - r0);
    }
    float v = acc / (float)(c1 - c0);
    mg[t] = (v > 0.5f) ? 1.0f : 0.0f;
  }
  __syncthreads();
  for (int i = t; i < 1024; i += 64){
    int r = i >> 5, c = i & 31;
    float m = mg[((r * 7) >> 5) * 7 + ((c * 7) >> 5)];
    bneg[((size_t)bh << 10) + i] = (m > 0.5f) ? 0.0f : NEGS;
  }
}

// ------------------------------------------------------------------
// 7/9) bf16 MFMA GEMM — dbuf global_load_lds(16B), BK=32, one barrier/step.
//   MODE 0: Q/K/V with LDS-staged coalesced epilogue (V transposed+perm).
//   MODE 1: Wo -> attnO bf16 [m][512] via same LDS-staged epilogue.
// ------------------------------------------------------------------
template<int MODE>
DI void gemm_body(const u16* __restrict__ A, const u16* __restrict__ Bw,
    const float* __restrict__ b0, const float* __restrict__ b1, const float* __restrict__ b2,
    u16* __restrict__ outQ, u16* __restrict__ outK, u16* __restrict__ outV, u16* __restrict__ outO){
  __shared__ __align__(16) u16 smem[16384];
  int m0 = blockIdx.x * 128, n0 = blockIdx.y * 128;
  bool vblk = (MODE == 0) && (n0 >= 1024);
  int t = threadIdx.x, lane = t & 63, w = t >> 6;
  int wr = w >> 1, wc = w & 1;
  int g = lane >> 4, li = lane & 15;
  f32x4 acc[4][4];
  #pragma unroll
  for (int mt = 0; mt < 4; mt++)
    #pragma unroll
    for (int nt = 0; nt < 4; nt++) acc[mt][nt] = (f32x4){0.f, 0.f, 0.f, 0.f};

  int cof = (((lane & 3) ^ ((lane >> 3) & 3)) << 3);
  int rl = lane >> 2;
  const u16* gA = A  + (size_t)(m0 + w * 32 + rl) * 512 + cof;
  const u16* gB = Bw + (size_t)(n0 + w * 32 + rl) * 512 + cof;
  u16* lA = smem + (w * 32) * 32;
  u16* lB = smem + 4096 + (w * 32) * 32;

  #define STAGE(buf, k0)                                              \
    gload16(gA + (k0),            lA + (buf) * 8192);                 \
    gload16(gA + (k0) + 16 * 512, lA + (buf) * 8192 + 512);           \
    gload16(gB + (k0),            lB + (buf) * 8192);                 \
    gload16(gB + (k0) + 16 * 512, lB + (buf) * 8192 + 512);

  STAGE(0, 0);
  __syncthreads();

  int rsw = ((li >> 1) & 3);
  int cA = (g ^ rsw) << 3;
  int cur = 0;
  for (int ks = 0; ks < 16; ks++){
    if (ks < 15){ STAGE(cur ^ 1, (ks + 1) * 32); }
    const u16* Ac = smem + cur * 8192;
    const u16* Bc = smem + cur * 8192 + 4096;
    bf16x8 afr[4], bfr[4];
    #pragma unroll
    for (int mt = 0; mt < 4; mt++)
      afr[mt] = *(const bf16x8*)&Ac[(wr * 64 + mt * 16 + li) * 32 + cA];
    #pragma unroll
    for (int nt = 0; nt < 4; nt++)
      bfr[nt] = *(const bf16x8*)&Bc[(wc * 64 + nt * 16 + li) * 32 + cA];
    if (vblk){
      #pragma unroll
      for (int mt = 0; mt < 4; mt++)
        #pragma unroll
        for (int nt = 0; nt < 4; nt++)
          acc[mt][nt] = __builtin_amdgcn_mfma_f32_16x16x32_bf16(afr[mt], bfr[nt], acc[mt][nt], 0, 0, 0);
    } else {
      #pragma unroll
      for (int mt = 0; mt < 4; mt++)
        #pragma unroll
        for (int nt = 0; nt < 4; nt++)
          acc[mt][nt] = __builtin_amdgcn_mfma_f32_16x16x32_bf16(bfr[nt], afr[mt], acc[mt][nt], 0, 0, 0);
    }
    __syncthreads();
    cur ^= 1;
  }
  #undef STAGE

  // ---- two-pass LDS-staged coalesced epilogue
  u16* Cl = smem;   // 64 x 136
  const float* bb = vblk ? b2 : ((MODE == 0 && (n0 >> 9)) ? b1 : b0);
  #pragma unroll
  for (int p = 0; p < 2; p++){
    __syncthreads();
    if (vblk){
      if (wc == p){
        #pragma unroll
        for (int mt = 0; mt < 4; mt++){
          #pragma unroll
          for (int nt = 0; nt < 4; nt++){
            int row = nt * 16 + li;
            float bias = bb[(n0 & 511) + p * 64 + row];
            int col = wr * 64 + ((mt >> 1) << 5) + (g << 3) + ((mt & 1) << 2);
            union { u32 d[2]; us4 v; } pu;
            pu.d[0] = cvtpk(acc[mt][nt][0] + bias, acc[mt][nt][1] + bias);
            pu.d[1] = cvtpk(acc[mt][nt][2] + bias, acc[mt][nt][3] + bias);
            *(us4*)&Cl[row * 136 + col] = pu.v;
          }
        }
      }
    } else {
      if (wr == p){
        #pragma unroll
        for (int mt = 0; mt < 4; mt++){
          #pragma unroll
          for (int nt = 0; nt < 4; nt++){
            int row = mt * 16 + li;
            int ob = wc * 64 + nt * 16 + (g << 2);
            float4 bias4 = *(const float4*)&bb[(n0 & 511) + ob];
            union { u32 d[2]; us4 v; } pu;
            pu.d[0] = cvtpk(acc[mt][nt][0] + bias4.x, acc[mt][nt][1] + bias4.y);
            pu.d[1] = cvtpk(acc[mt][nt][2] + bias4.z, acc[mt][nt][3] + bias4.w);
            *(us4*)&Cl[row * 136 + ob] = pu.v;
          }
        }
      }
    }
    __syncthreads();
    int r = t >> 4, ol = (t & 15) << 3;
    if (vblk){
      int b = m0 >> 10, nt0 = m0 & 1023;
      #pragma unroll
      for (int pp = 0; pp < 4; pp++){
        int rr = pp * 16 + r;
        int c = (n0 & 511) + p * 64 + rr, h = c >> 6, dv = c & 63;
        us8 v = *(us8*)&Cl[rr * 136 + ol];
        *(us8*)&outV[(((size_t)(b * 8 + h)) << 16) + ((size_t)dv << 10) + nt0 + ol] = v;
      }
    } else if (MODE == 0){
      u16* base = (n0 >> 9) ? outK : outQ;
      #pragma unroll
      for (int pp = 0; pp < 4; pp++){
        int rr = pp * 16 + r;
        int m = m0 + p * 64 + rr, b = m >> 10, n = m & 1023;
        int c = (n0 & 511) + ol, h = c >> 6, dv = c & 63;
        us8 v = *(us8*)&Cl[rr * 136 + ol];
        *(us8*)&base[(((size_t)(b * 8 + h)) << 16) + ((size_t)n << 6) + dv] = v;
      }
    } else {
      // MODE 1: attnO bf16, [m][512] rows; 16 lanes x us8 = 256B contiguous
      #pragma unroll
      for (int pp = 0; pp < 4; pp++){
        int rr = pp * 16 + r;
        int m = m0 + p * 64 + rr;
        us8 v = *(us8*)&Cl[rr * 136 + ol];
        *(us8*)&outO[((size_t)m << 9) + n0 + ol] = v;
      }
    }
  }
}

__global__ __launch_bounds__(256) void k_gemm_qkv(const u16* __restrict__ A, const u16* __restrict__ Bw,
    const float* __restrict__ b0, const float* __restrict__ b1, const float* __restrict__ b2,
    u16* __restrict__ outQ, u16* __restrict__ outK, u16* __restrict__ outV){
  gemm_body<0>(A, Bw, b0, b1, b2, outQ, outK, outV, nullptr);
}

__global__ __launch_bounds__(256) void k_gemm_o(const u16* __restrict__ A, const u16* __restrict__ Bw,
    const float* __restrict__ b0, u16* __restrict__ outO){
  gemm_body<1>(A, Bw, b0, nullptr, nullptr, nullptr, nullptr, nullptr, outO);
}

// ------------------------------------------------------------------
// 8) flash attention: 32 q-rows/wave (2 groups sharing K/V frag reads),
//    pitch-88 conflict-free LDS, double-buffered (1 barrier/tile),
//    base-2 softmax, cvt_pk, defer-max, XCD swizzle, setprio.
//    512 blocks = 64 bh x 8 q-tiles(128 rows); 4 waves x 32 q-rows.
// ------------------------------------------------------------------
__global__ __launch_bounds__(256) void k_flash(const u16* __restrict__ Q, const u16* __restrict__ K,
    const u16* __restrict__ Vt, const float* __restrict__ bneg, u16* __restrict__ attnB){
  __shared__ __align__(16) u16 Ks[2][64 * 88];
  __shared__ __align__(16) u16 Vts[2][64 * 88];
  __shared__ float mks[2][64];
  int hw = blockIdx.x;
  int bid = ((hw & 7) << 6) + (hw >> 3);   // 512 blocks: each XCD gets 8 whole bh
  int bh = bid >> 3, q0 = (bid & 7) << 7;
  int t = threadIdx.x, lane = t & 63, w = t >> 6;
  int g = lane >> 4, li = lane & 15;

  const u16* Kp = K  + ((size_t)bh << 16);
  const u16* Vp = Vt + ((size_t)bh << 16);
  const float* bp = bneg + ((size_t)bh << 10);

  bf16x8 qf0a, qf1a, qf0b, qf1b;
  {
    const u16* qra = Q + ((size_t)bh << 16) + ((size_t)(q0 + w * 32 + li) << 6);
    qf0a = *(const bf16x8*)(qra + g * 8);
    qf1a = *(const bf16x8*)(qra + 32 + g * 8);
    const u16* qrb = qra + (16 << 6);
    qf0b = *(const bf16x8*)(qrb + g * 8);
    qf1b = *(const bf16x8*)(qrb + 32 + g * 8);
  }
  float bnqa = bp[q0 + w * 32 + li];
  float bnqb = bp[q0 + w * 32 + 16 + li];

  f32x4 oaccA[4], oaccB[4];
  #pragma unroll
  for (int dt = 0; dt < 4; dt++){
    oaccA[dt] = (f32x4){0.f, 0.f, 0.f, 0.f};
    oaccB[dt] = (f32x4){0.f, 0.f, 0.f, 0.f};
  }
  float mrunA = -INFINITY, lrunA = 0.0f, mrunB = -INFINITY, lrunB = 0.0f;

  int sr = t >> 2, sc = (t & 3) << 4;
  const u16* kg = Kp + ((size_t)sr << 6) + sc;
  const u16* vg = Vp + ((size_t)sr << 10) + sc;
  uint4 kr0 = *(const uint4*)(kg), kr1 = *(const uint4*)(kg + 8);
  uint4 vr0 = *(const uint4*)(vg), vr1 = *(const uint4*)(vg + 8);
  float mr = (t < 64) ? bp[t] : 0.0f;

  *(uint4*)&Ks[0][sr * 88 + sc]      = kr0;
  *(uint4*)&Ks[0][sr * 88 + sc + 8]  = kr1;
  *(uint4*)&Vts[0][sr * 88 + sc]     = vr0;
  *(uint4*)&Vts[0][sr * 88 + sc + 8] = vr1;
  if (t < 64) mks[0][t] = mr;
  __syncthreads();

  for (int kt = 0; kt < 16; kt++){
    int buf = kt & 1;
    if (kt < 15){
      kr0 = *(const uint4*)(kg + (kt + 1) * 4096);
      kr1 = *(const uint4*)(kg + (kt + 1) * 4096 + 8);
      vr0 = *(const uint4*)(vg + (kt + 1) * 64);
      vr1 = *(const uint4*)(vg + (kt + 1) * 64 + 8);
      if (t < 64) mr = bp[(kt + 1) * 64 + t];
    }

    // S^T = K Q^T, both q-groups share each K fragment read
    f32x4 sa[4], sb[4];
    #pragma unroll
    for (int mt = 0; mt < 4; mt++){ sa[mt] = (f32x4){0.f,0.f,0.f,0.f}; sb[mt] = (f32x4){0.f,0.f,0.f,0.f}; }
    __builtin_amdgcn_s_setprio(1);
    #pragma unroll
    for (int mt = 0; mt < 4; mt++){
      bf16x8 kf0 = *(bf16x8*)&Ks[buf][(mt * 16 + li) * 88 + g * 8];
      bf16x8 kf1 = *(bf16x8*)&Ks[buf][(mt * 16 + li) * 88 + 32 + g * 8];
      sa[mt] = __builtin_amdgcn_mfma_f32_16x16x32_bf16(kf0, qf0a, sa[mt], 0, 0, 0);
      sa[mt] = __builtin_amdgcn_mfma_f32_16x16x32_bf16(kf1, qf1a, sa[mt], 0, 0, 0);
      sb[mt] = __builtin_amdgcn_mfma_f32_16x16x32_bf16(kf0, qf0b, sb[mt], 0, 0, 0);
      sb[mt] = __builtin_amdgcn_mfma_f32_16x16x32_bf16(kf1, qf1b, sb[mt], 0, 0, 0);
    }
    __builtin_amdgcn_s_setprio(0);

    // ---- softmax group A
    union { u32 d[4]; bf16x8 v; } u0a, u1a, u0b, u1b;
    {
      float tm[4];
      #pragma unroll
      for (int mt = 0; mt < 4; mt++){
        float4 bk = *(const float4*)&mks[buf][mt * 16 + g * 4];
        float s0 = fmaf(sa[mt][0], QKSCL, fminf(bk.x, bnqa));
        float s1 = fmaf(sa[mt][1], QKSCL, fminf(bk.y, bnqa));
        float s2 = fmaf(sa[mt][2], QKSCL, fminf(bk.z, bnqa));
        float s3 = fmaf(sa[mt][3], QKSCL, fminf(bk.w, bnqa));
        sa[mt][0] = s0; sa[mt][1] = s1; sa[mt][2] = s2; sa[mt][3] = s3;
        tm[mt] = fmaxf(fmaxf(s0, s1), fmaxf(s2, s3));
      }
      float tmax = fmaxf(fmaxf(tm[0], tm[1]), fmaxf(tm[2], tm[3]));
      tmax = fmaxf(tmax, __shfl_xor(tmax, 16, 64));
      tmax = fmaxf(tmax, __shfl_xor(tmax, 32, 64));
      if (!__all(tmax <= mrunA + DEFTH)){
        float mnew = fmaxf(mrunA, tmax);
        float scl = exp2a(mrunA - mnew);
        mrunA = mnew; lrunA *= scl;
        #pragma unroll
        for (int dt = 0; dt < 4; dt++)
          #pragma unroll
          for (int j = 0; j < 4; j++) oaccA[dt][j] *= scl;
      }
      float rs[4];
      #pragma unroll
      for (int mt = 0; mt < 4; mt++){
        float p0 = exp2a(sa[mt][0] - mrunA);
        float p1 = exp2a(sa[mt][1] - mrunA);
        float p2 = exp2a(sa[mt][2] - mrunA);
        float p3 = exp2a(sa[mt][3] - mrunA);
        sa[mt][0] = p0; sa[mt][1] = p1; sa[mt][2] = p2; sa[mt][3] = p3;
        rs[mt] = (p0 + p1) + (p2 + p3);
      }
      float rsum = (rs[0] + rs[1]) + (rs[2] + rs[3]);
      rsum += __shfl_xor(rsum, 16, 64);
      rsum += __shfl_xor(rsum, 32, 64);
      lrunA += rsum;
      u0a.d[0] = cvtpk(sa[0][0], sa[0][1]); u0a.d[1] = cvtpk(sa[0][2], sa[0][3]);
      u0a.d[2] = cvtpk(sa[1][0], sa[1][1]); u0a.d[3] = cvtpk(sa[1][2], sa[1][3]);
      u1a.d[0] = cvtpk(sa[2][0], sa[2][1]); u1a.d[1] = cvtpk(sa[2][2], sa[2][3]);
      u1a.d[2] = cvtpk(sa[3][0], sa[3][1]); u1a.d[3] = cvtpk(sa[3][2], sa[3][3]);
    }
    // ---- softmax group B
    {
      float tm[4];
      #pragma unroll
      for (int mt = 0; mt < 4; mt++){
        float4 bk = *(const float4*)&mks[buf][mt * 16 + g * 4];
        float s0 = fmaf(sb[mt][0], QKSCL, fminf(bk.x, bnqb));
        float s1 = fmaf(sb[mt][1], QKSCL, fminf(bk.y, bnqb));
        float s2 = fmaf(sb[mt][2], QKSCL, fminf(bk.z, bnqb));
        float s3 = fmaf(sb[mt][3], QKSCL, fminf(bk.w, bnqb));
        sb[mt][0] = s0; sb[mt][1] = s1; sb[mt][2] = s2; sb[mt][3] = s3;
        tm[mt] = fmaxf(fmaxf(s0, s1), fmaxf(s2, s3));
      }
      float tmax = fmaxf(fmaxf(tm[0], tm[1]), fmaxf(tm[2], tm[3]));
      tmax = fmaxf(tmax, __shfl_xor(tmax, 16, 64));
      tmax = fmaxf(tmax, __shfl_xor(tmax, 32, 64));
      if (!__all(tmax <= mrunB + DEFTH)){
        float mnew = fmaxf(mrunB, tmax);
        float scl = exp2a(mrunB - mnew);
        mrunB = mnew; lrunB *= scl;
        #pragma unroll
        for (int dt = 0; dt < 4; dt++)
          #pragma unroll
          for (int j = 0; j < 4; j++) oaccB[dt][j] *= scl;
      }
      float rs[4];
      #pragma unroll
      for (int mt = 0; mt < 4; mt++){
        float p0 = exp2a(sb[mt][0] - mrunB);
        float p1 = exp2a(sb[mt][1] - mrunB);
        float p2 = exp2a(sb[mt][2] - mrunB);
        float p3 = exp2a(sb[mt][3] - mrunB);
        sb[mt][0] = p0; sb[mt][1] = p1; sb[mt][2] = p2; sb[mt][3] = p3;
        rs[mt] = (p0 + p1) + (p2 + p3);
      }
      float rsum = (rs[0] + rs[1]) + (rs[2] + rs[3]);
      rsum += __shfl_xor(rsum, 16, 64);
      rsum += __shfl_xor(rsum, 32, 64);
      lrunB += rsum;
      u0b.d[0] = cvtpk(sb[0][0], sb[0][1]); u0b.d[1] = cvtpk(sb[0][2], sb[0][3]);
      u0b.d[2] = cvtpk(sb[1][0], sb[1][1]); u0b.d[3] = cvtpk(sb[1][2], sb[1][3]);
      u1b.d[0] = cvtpk(sb[2][0], sb[2][1]); u1b.d[1] = cvtpk(sb[2][2], sb[2][3]);
      u1b.d[2] = cvtpk(sb[3][0], sb[3][1]); u1b.d[3] = cvtpk(sb[3][2], sb[3][3]);
    }

    // O^T += Vt P, both groups share each V fragment read
    __builtin_amdgcn_s_setprio(1);
    #pragma unroll
    for (int dt = 0; dt < 4; dt++){
      bf16x8 vf0 = *(bf16x8*)&Vts[buf][(dt * 16 + li) * 88 + g * 8];
      bf16x8 vf1 = *(bf16x8*)&Vts[buf][(dt * 16 + li) * 88 + 32 + g * 8];
      oaccA[dt] = __builtin_amdgcn_mfma_f32_16x16x32_bf16(vf0, u0a.v, oaccA[dt], 0, 0, 0);
      oaccA[dt] = __builtin_amdgcn_mfma_f32_16x16x32_bf16(vf1, u1a.v, oaccA[dt], 0, 0, 0);
      oaccB[dt] = __builtin_amdgcn_mfma_f32_16x16x32_bf16(vf0, u0b.v, oaccB[dt], 0, 0, 0);
      oaccB[dt] = __builtin_amdgcn_mfma_f32_16x16x32_bf16(vf1, u1b.v, oaccB[dt], 0, 0, 0);
    }
    __builtin_amdgcn_s_setprio(0);

    if (kt < 15){
      int nb = buf ^ 1;
      *(uint4*)&Ks[nb][sr * 88 + sc]      = kr0;
      *(uint4*)&Ks[nb][sr * 88 + sc + 8]  = kr1;
      *(uint4*)&Vts[nb][sr * 88 + sc]     = vr0;
      *(uint4*)&Vts[nb][sr * 88 + sc + 8] = vr1;
      if (t < 64) mks[nb][t] = mr;
      __syncthreads();
    }
  }

  int b = bh >> 3, h = bh & 7;
  float invA = 1.0f / lrunA, invB = 1.0f / lrunB;
  u16* opA = attnB + (((size_t)(b * 1024 + q0 + w * 32 + li)) << 9) + h * 64 + g * 4;
  u16* opB = opA + (16 << 9);
  #pragma unroll
  for (int dt = 0; dt < 4; dt++){
    union { u32 d[2]; us4 v; } oa, ob;
    oa.d[0] = cvtpk(oaccA[dt][0] * invA, oaccA[dt][1] * invA);
    oa.d[1] = cvtpk(oaccA[dt][2] * invA, oaccA[dt][3] * invA);
    ob.d[0] = cvtpk(oaccB[dt][0] * invB, oaccB[dt][1] * invB);
    ob.d[1] = cvtpk(oaccB[dt][2] * invB, oaccB[dt][3] * invB);
    *(us4*)(opA + dt * 16) = oa.v;
    *(us4*)(opB + dt * 16) = ob.v;
  }
}

// ------------------------------------------------------------------
// 10) LN over C + transpose to (B,C,N)  (attnO now bf16)
// ------------------------------------------------------------------
__global__ __launch_bounds__(256) void k_ln(const u16* __restrict__ xfB, const u16* __restrict__ attnO,
    const float* __restrict__ gamma, const float* __restrict__ beta, float* __restrict__ out){
  __shared__ float mu_s[64], rs_s[64];
  __shared__ float tile[64][65];
  int b = blockIdx.x >> 4, n0 = (blockIdx.x & 15) << 6;
  int t = threadIdx.x, w = t >> 6, lane = t & 63;

  for (int r = w * 16; r < w * 16 + 16; r++){
    size_t rb = ((size_t)(b * 1024 + n0 + r)) << 9;
    union { uint4 v; u16 u[8]; } av; av.v = *(const uint4*)(attnO + rb + lane * 8);
    union { uint4 v; u16 u[8]; } xv; xv.v = *(const uint4*)(xfB + rb + lane * 8);
    float s = 0.0f, s2 = 0.0f;
    #pragma unroll
    for (int i = 0; i < 8; i++){
      float v = b2f(av.u[i]) + b2f(xv.u[i]);
      s += v; s2 += v * v;
    }
    #pragma unroll
    for (int o = 32; o > 0; o >>= 1){ s += __shfl_xor(s, o, 64); s2 += __shfl_xor(s2, o, 64); }
    if (lane == 0){
      float mu = s * (1.0f / 512.0f);
      float var = s2 * (1.0f / 512.0f) - mu * mu;
      mu_s[r] = mu;
      rs_s[r] = 1.0f / sqrtf(var + 1e-5f);
    }
  }
  __syncthreads();

  for (int ch = 0; ch < 8; ch++){
    int c0 = ch * 64;
    {
      int r = t >> 2, cp = (t & 3) << 4;
      size_t rb = (((size_t)(b * 1024 + n0 + r)) << 9) + c0 + cp;
      float mu = mu_s[r], rstd = rs_s[r];
      #pragma unroll
      for (int i2 = 0; i2 < 2; i2++){
        union { uint4 v; u16 u[8]; } av; av.v = *(const uint4*)(attnO + rb + i2 * 8);
        union { uint4 v; u16 u[8]; } xv; xv.v = *(const uint4*)(xfB + rb + i2 * 8);
        #pragma unroll
        for (int i = 0; i < 8; i++){
          int c = c0 + cp + i2 * 8 + i;
          float v = b2f(av.u[i]) + b2f(xv.u[i]);
          tile[r][cp + i2 * 8 + i] = (v - mu) * rstd * gamma[c] + beta[c];
        }
      }
    }
    __syncthreads();
    {
      int cl = t >> 2, np_ = (t & 3) << 4;
      float* op = out + (((size_t)(b * 512 + c0 + cl)) << 10) + n0 + np_;
      #pragma unroll
      for (int i = 0; i < 16; i += 4){
        float4 vo = { tile[np_ + i][cl], tile[np_ + i + 1][cl], tile[np_ + i + 2][cl], tile[np_ + i + 3][cl] };
        *(float4*)(op + i) = vo;
      }
    }
    __syncthreads();
  }
}

// ------------------------------------------------------------------
extern "C" void kernel_launch(void* const* d_in, const int* in_sizes, int n_in,
                              void* d_out, int out_size, void* d_ws, size_t ws_size,
                              hipStream_t stream){
  (void)in_sizes; (void)n_in; (void)out_size; (void)ws_size;
  const float* x    = (const float*)d_in[0];
  const float* Wq   = (const float*)d_in[1];
  const float* bq   = (const float*)d_in[2];
  const float* Wk   = (const float*)d_in[3];
  const float* bk   = (const float*)d_in[4];
  const float* Wv   = (const float*)d_in[5];
  const float* bv   = (const float*)d_in[6];
  const float* Wo   = (const float*)d_in[7];
  const float* bo   = (const float*)d_in[8];
  const float* Wsp  = (const float*)d_in[9];
  const float* bsp  = (const float*)d_in[10];
  const float* Wse1 = (const float*)d_in[11];
  const float* bse1 = (const float*)d_in[12];
  const float* Wse2 = (const float*)d_in[13];
  const float* bse2 = (const float*)d_in[14];
  const float* gamma= (const float*)d_in[15];
  const float* beta = (const float*)d_in[16];
  float* out = (float*)d_out;

  char* ws = (char*)d_ws;
  size_t off = 0;
  auto alloc = [&](size_t bytes) -> void* {
    void* p = ws + off;
    off += (bytes + 255) & ~(size_t)255;
    return p;
  };
  u16*   WB     = (u16*)  alloc(1536 * 512 * 2);
  u16*   WoB    = (u16*)  alloc(512 * 512 * 2);
  float* pooled = (float*)alloc(4096 * 4);
  float* cw     = (float*)alloc(4096 * 4);
  float* mbuf   = (float*)alloc(65536 * 4);
  float* bneg   = (float*)alloc(65536 * 4);
  u16*   xfB    = (u16*)  alloc((size_t)8192 * 512 * 2);
  u16*   Qb     = (u16*)  alloc(8388608);
  u16*   Kb     = (u16*)  alloc(8388608);
  u16*   VtG    = (u16*)  alloc(8388608);
  u16*   attnB  = (u16*)  alloc(8388608);
  u16*   attnOb = Qb;   // alias Q (8.4MB) after flash

  k_cvt   <<<dim3(1024), dim3(256), 0, stream>>>(Wq, Wk, Wv, Wo, WB, WoB);
  k_pooled<<<dim3(1024), dim3(256), 0, stream>>>(x, pooled);
  k_se    <<<dim3(8),    dim3(256), 0, stream>>>(pooled, Wse1, bse1, Wse2, bse2, cw);
  k_spxf  <<<dim3(256),  dim3(256), 0, stream>>>(x, Wsp, bsp, cw, mbuf, xfB);
  k_mask  <<<dim3(64),   dim3(64),  0, stream>>>(mbuf, bneg);
  k_gemm_qkv<<<dim3(64, 12), dim3(256), 0, stream>>>(xfB, WB, bq, bk, bv, Qb, Kb, VtG);
  k_flash <<<dim3(512),  dim3(256), 0, stream>>>(Qb, Kb, VtG, bneg, attnB);
  k_gemm_o<<<dim3(64, 4), dim3(256), 0, stream>>>(attnB, WoB, bo, attnOb);
  k_ln    <<<dim3(128),  dim3(256), 0, stream>>>(xfB, attnOb, gamma, beta, out);
}